// Round 1
// baseline (6826.330 us; speedup 1.0000x reference)
//
#include <hip/hip_runtime.h>
#include <cstdint>
#include <cstddef>

// ---------------- constants ----------------
static constexpr int NIMG = 2;
static constexpr int CCH  = 256;                  // channels
static constexpr int LTOT = 261888;               // sum H*W*3 over levels
static constexpr int MCAT = 4768;                 // 1000*4 + 768
static constexpr int MW   = 75;                   // ceil(4768/64)
static constexpr double SCALE_CLAMP_D = 4.135166556742356; // ln(1000/16)

// ---------------- key helpers (descending-order monotone uint key) --------
__device__ __forceinline__ unsigned keyd(float f) {
  unsigned u = __float_as_uint(f);
  return (u >> 31) ? ~u : (u | 0x80000000u);
}
__device__ __forceinline__ float invkey(unsigned d) {
  unsigned u = (d & 0x80000000u) ? (d & 0x7FFFFFFFu) : ~d;
  return __uint_as_float(u);
}

// ---------------- K0: transpose conv weights [O][I][3][3] -> [I*9][O] -----
__global__ void k_wT(const float* __restrict__ w, float* __restrict__ wT) {
  int i = blockIdx.x * 256 + threadIdx.x;
  if (i >= 2304 * 256) return;
  int co = i & 255;
  int ct = i >> 8;                 // ci*9 + tap
  wT[ct * 256 + co] = w[co * 2304 + ct];
}

// ---------------- K1: conv3x3 + bias + relu (fp32) ------------------------
// block tile: 64 couts x (4 rows x 64 cols). 256 threads, each 8co x 8col.
__global__ __launch_bounds__(256)
void k_conv(const float* __restrict__ x, const float* __restrict__ wT,
            const float* __restrict__ bias, float* __restrict__ t,
            int H, int W) {
  __shared__ float xs[8][6][68];
  __shared__ float wsm[8][9][64];
  const int HW = H * W;
  const int n    = blockIdx.z >> 2;
  const int cog  = blockIdx.z & 3;
  const int cout0 = cog * 64;
  const int h0 = blockIdx.y * 4;
  const int w0 = blockIdx.x * 64;
  const int tx = threadIdx.x;
  const int cg8  = tx >> 5;        // 0..7 -> couts cout0+cg8*8 ..+7
  const int rw   = (tx >> 3) & 3;  // row 0..3
  const int colg = tx & 7;         // col group
  const int col0 = colg * 8;

  float acc[8][8];
#pragma unroll
  for (int a = 0; a < 8; ++a)
#pragma unroll
    for (int b = 0; b < 8; ++b) acc[a][b] = 0.f;

  for (int ck = 0; ck < 32; ++ck) {
    // stage x tile (8 cin x 6 rows x 66 cols, zero-padded halo)
    for (int i = tx; i < 8 * 6 * 66; i += 256) {
      int ci = i / 396;
      int r  = (i - ci * 396) / 66;
      int c  = i - ci * 396 - r * 66;
      int gh = h0 - 1 + r, gw = w0 - 1 + c;
      float v = 0.f;
      if ((unsigned)gh < (unsigned)H && (unsigned)gw < (unsigned)W)
        v = x[((size_t)(n * CCH + ck * 8 + ci) * H + gh) * W + gw];
      xs[ci][r][c] = v;
    }
    // stage w tile (8 cin x 9 taps x 64 couts), coalesced from wT
    for (int i = tx; i < 8 * 9 * 64; i += 256) {
      int ci = i / 576;
      int rem = i - ci * 576;
      int tap = rem >> 6;
      int co  = rem & 63;
      wsm[ci][tap][co] = wT[((size_t)(ck * 8 + ci) * 9 + tap) * 256 + cout0 + co];
    }
    __syncthreads();

#pragma unroll
    for (int ci = 0; ci < 8; ++ci) {
      float xr[3][10];
#pragma unroll
      for (int kh = 0; kh < 3; ++kh) {
        const float* p = &xs[ci][rw + kh][col0];
        float4 a0 = *reinterpret_cast<const float4*>(p);
        float4 a1 = *reinterpret_cast<const float4*>(p + 4);
        float2 a2 = *reinterpret_cast<const float2*>(p + 8);
        xr[kh][0]=a0.x; xr[kh][1]=a0.y; xr[kh][2]=a0.z; xr[kh][3]=a0.w;
        xr[kh][4]=a1.x; xr[kh][5]=a1.y; xr[kh][6]=a1.z; xr[kh][7]=a1.w;
        xr[kh][8]=a2.x; xr[kh][9]=a2.y;
      }
#pragma unroll
      for (int kh = 0; kh < 3; ++kh)
#pragma unroll
        for (int kw = 0; kw < 3; ++kw) {
          const float* wp = &wsm[ci][kh * 3 + kw][cg8 * 8];
          float4 wa = *reinterpret_cast<const float4*>(wp);
          float4 wb = *reinterpret_cast<const float4*>(wp + 4);
          float wv[8] = {wa.x, wa.y, wa.z, wa.w, wb.x, wb.y, wb.z, wb.w};
#pragma unroll
          for (int co = 0; co < 8; ++co)
#pragma unroll
            for (int cl = 0; cl < 8; ++cl)
              acc[co][cl] = fmaf(xr[kh][cl + kw], wv[co], acc[co][cl]);
        }
    }
    __syncthreads();
  }

  const int h = h0 + rw;
#pragma unroll
  for (int co = 0; co < 8; ++co) {
    int c = cout0 + cg8 * 8 + co;
    float bv = bias[c];
#pragma unroll
    for (int cl = 0; cl < 8; ++cl) {
      int ww = w0 + col0 + cl;
      if (ww < W) {
        float v = acc[co][cl] + bv;
        t[((size_t)(n * CCH + c) * H + h) * W + ww] = v > 0.f ? v : 0.f;
      }
    }
  }
}

// ---------------- K2: 1x1 heads -> logits + deltas ------------------------
__global__ __launch_bounds__(256)
void k_heads(const float* __restrict__ t,
             const float* __restrict__ wobj, const float* __restrict__ bobj,
             const float* __restrict__ wdel, const float* __restrict__ bdel,
             float* __restrict__ logits, float4* __restrict__ deltas,
             int HW, int loff) {
  __shared__ float wl[15][256];
  __shared__ float bl[15];
  for (int i = threadIdx.x; i < 15 * 256; i += 256) {
    int o = i >> 8, c = i & 255;
    wl[o][c] = (o < 3) ? wobj[o * 256 + c] : wdel[(o - 3) * 256 + c];
  }
  if (threadIdx.x < 15)
    bl[threadIdx.x] = (threadIdx.x < 3) ? bobj[threadIdx.x] : bdel[threadIdx.x - 3];
  __syncthreads();

  int n = blockIdx.y;
  int p = blockIdx.x * 256 + threadIdx.x;
  if (p >= HW) return;

  float acc[15];
#pragma unroll
  for (int o = 0; o < 15; ++o) acc[o] = 0.f;
  const float* tp = t + (size_t)n * CCH * HW + p;
  for (int c = 0; c < 256; ++c) {
    float v = tp[(size_t)c * HW];
#pragma unroll
    for (int o = 0; o < 15; ++o) acc[o] = fmaf(v, wl[o][c], acc[o]);
  }
#pragma unroll
  for (int o = 0; o < 15; ++o) acc[o] += bl[o];

  size_t base = (size_t)n * LTOT + loff + (size_t)p * 3;
#pragma unroll
  for (int a = 0; a < 3; ++a) {
    logits[base + a] = acc[a];
    deltas[base + a] = make_float4(acc[3 + a * 4 + 0], acc[3 + a * 4 + 1],
                                   acc[3 + a * 4 + 2], acc[3 + a * 4 + 3]);
  }
}

// ---------------- K3: per-(n,level) exact stable top-k + box decode -------
__global__ __launch_bounds__(1024)
void k_topk(const float* __restrict__ logits, const float4* __restrict__ deltas,
            float* __restrict__ scat, float4* __restrict__ bout,
            double* __restrict__ obout, unsigned* __restrict__ valid) {
  constexpr int   Hs[5]    = {256, 128, 64, 32, 16};
  constexpr int   strd[5]  = {4, 8, 16, 32, 64};
  constexpr float szs[5]   = {32.f, 64.f, 128.f, 256.f, 512.f};
  constexpr int   loffs[5] = {0, 196608, 245760, 258048, 261120};
  constexpr int   Ms[5]    = {196608, 49152, 12288, 3072, 768};
  constexpr int   ksz[5]   = {1000, 1000, 1000, 1000, 768};
  constexpr int   coffs[5] = {0, 1000, 2000, 3000, 4000};

  __shared__ unsigned hist[2048];
  __shared__ unsigned long long cand[1024];
  __shared__ unsigned tie[1024];
  __shared__ unsigned sB1, sC1, sB2, sC2, sDK, sTN;
  __shared__ unsigned cntG, cntT;

  const int task = blockIdx.x;
  const int n = task / 5, lvl = task % 5;
  const int M = Ms[lvl], K = ksz[lvl], loff = loffs[lvl];
  const float* lg = logits + (size_t)n * LTOT + loff;
  const int tid = threadIdx.x;

  // pass 1: top 11 bits
  for (int i = tid; i < 2048; i += 1024) hist[i] = 0;
  if (tid == 0) { cntG = 0; cntT = 0; }
  __syncthreads();
  for (int i = tid; i < M; i += 1024) atomicAdd(&hist[keyd(lg[i]) >> 21], 1u);
  __syncthreads();
  if (tid == 0) {
    unsigned acc = 0;
    for (int b = 2047; b >= 0; --b) {
      unsigned na = acc + hist[b];
      if (na >= (unsigned)K) { sB1 = (unsigned)b; sC1 = acc; break; }
      acc = na;
    }
  }
  __syncthreads();
  const unsigned B1 = sB1;
  const unsigned rem1 = (unsigned)K - sC1;

  // pass 2: next 11 bits
  for (int i = tid; i < 2048; i += 1024) hist[i] = 0;
  __syncthreads();
  for (int i = tid; i < M; i += 1024) {
    unsigned d = keyd(lg[i]);
    if ((d >> 21) == B1) atomicAdd(&hist[(d >> 10) & 0x7FFu], 1u);
  }
  __syncthreads();
  if (tid == 0) {
    unsigned acc = 0;
    for (int b = 2047; b >= 0; --b) {
      unsigned na = acc + hist[b];
      if (na >= rem1) { sB2 = (unsigned)b; sC2 = acc; break; }
      acc = na;
    }
  }
  __syncthreads();
  const unsigned B2 = sB2;
  const unsigned rem2 = rem1 - sC2;
  const unsigned pfx = (B1 << 11) | B2;

  // pass 3: low 10 bits -> exact k-th key
  for (int i = tid; i < 1024; i += 1024) hist[i] = 0;
  __syncthreads();
  for (int i = tid; i < M; i += 1024) {
    unsigned d = keyd(lg[i]);
    if ((d >> 10) == pfx) atomicAdd(&hist[d & 0x3FFu], 1u);
  }
  __syncthreads();
  if (tid == 0) {
    unsigned acc = 0;
    for (int b = 1023; b >= 0; --b) {
      unsigned na = acc + hist[b];
      if (na >= rem2) { sDK = (pfx << 10) | (unsigned)b; sTN = rem2 - acc; break; }
      acc = na;
    }
  }
  __syncthreads();
  const unsigned dk = sDK;
  const unsigned tneed = sTN;
  const unsigned cg = (unsigned)K - tneed;

  // pass 4: compact strictly-greater + ties
  for (int i = tid; i < M; i += 1024) {
    unsigned d = keyd(lg[i]);
    if (d > dk) {
      unsigned p = atomicAdd(&cntG, 1u);
      cand[p] = ((unsigned long long)(~d) << 32) | (unsigned)i;
    } else if (d == dk) {
      unsigned q = atomicAdd(&cntT, 1u);
      if (q < 1024u) tie[q] = (unsigned)i;
    }
  }
  __syncthreads();
  if (tid == 0) {
    int ct = (int)(cntT < 1024u ? cntT : 1024u);
    for (int a = 1; a < ct; ++a) {            // insertion sort (ascending index)
      unsigned v = tie[a]; int b = a - 1;
      while (b >= 0 && tie[b] > v) { tie[b + 1] = tie[b]; --b; }
      tie[b + 1] = v;
    }
    for (unsigned q = 0; q < tneed; ++q)
      cand[cg + q] = ((unsigned long long)(~dk) << 32) | tie[q];
  }
  __syncthreads();
  if (tid >= K) cand[tid] = ~0ULL;           // pad (tid<1024)
  __syncthreads();

  // bitonic sort 1024 ascending (key = (~d)<<32 | idx  => score desc, idx asc)
  for (unsigned k2 = 2; k2 <= 1024; k2 <<= 1)
    for (unsigned j = k2 >> 1; j > 0; j >>= 1) {
      __syncthreads();
      unsigned i = (unsigned)tid, l = i ^ j;
      if (l > i) {
        unsigned long long a = cand[i], b = cand[l];
        bool up = ((i & k2) == 0);
        if (up ? (a > b) : (a < b)) { cand[i] = b; cand[l] = a; }
      }
    }
  __syncthreads();

  if (tid < K) {
    unsigned long long kk = cand[tid];
    unsigned idx = (unsigned)kk;
    unsigned d = ~(unsigned)(kk >> 32);
    float s = invkey(d);
    int catpos = n * MCAT + coffs[lvl] + tid;
    scat[catpos] = s;

    int a = idx % 3;
    int pix = idx / 3;
    int W = Hs[lvl];
    int hh = pix / W;
    int ww = pix - hh * W;
    float4 d4 = deltas[(size_t)n * LTOT + loff + idx];

    double r  = (a == 0) ? 0.5 : (a == 1 ? 1.0 : 2.0);
    double sz = (double)szs[lvl];
    double cw = sz / sqrt(r);
    double ch = cw * r;
    double cx = (double)(ww * strd[lvl]);
    double cy = (double)(hh * strd[lvl]);
    double dx = (double)d4.x, dy = (double)d4.y;
    double dw = (double)d4.z; if (dw > SCALE_CLAMP_D) dw = SCALE_CLAMP_D;
    double dh = (double)d4.w; if (dh > SCALE_CLAMP_D) dh = SCALE_CLAMP_D;
    double pcx = dx * cw + cx, pcy = dy * ch + cy;
    double pw = exp(dw) * cw,  ph = exp(dh) * ch;
    double x0 = pcx - 0.5 * pw, y0 = pcy - 0.5 * ph;
    double x1 = pcx + 0.5 * pw, y1 = pcy + 0.5 * ph;
    x0 = x0 < 0.0 ? 0.0 : (x0 > 1024.0 ? 1024.0 : x0);
    y0 = y0 < 0.0 ? 0.0 : (y0 > 1024.0 ? 1024.0 : y0);
    x1 = x1 < 0.0 ? 0.0 : (x1 > 1024.0 ? 1024.0 : x1);
    y1 = y1 < 0.0 ? 0.0 : (y1 > 1024.0 ? 1024.0 : y1);
    bool vld = ((x1 - x0) > 0.0) && ((y1 - y0) > 0.0);

    bout[catpos] = make_float4((float)x0, (float)y0, (float)x1, (float)y1);
    double off = (double)lvl * 4096.0;
    double* op = obout + (size_t)catpos * 4;
    op[0] = x0 + off; op[1] = y0 + off; op[2] = x1 + off; op[3] = y1 + off;
    valid[catpos] = vld ? 1u : 0u;
  }
}

// ---------------- K4: per-image stable sort of 4768 candidates ------------
__global__ __launch_bounds__(1024)
void k_sort(const float* __restrict__ scat, const float4* __restrict__ b,
            const double* __restrict__ ob, const unsigned* __restrict__ valid,
            float* __restrict__ s_s, float4* __restrict__ b_s,
            double* __restrict__ ob_s, unsigned* __restrict__ valid_s) {
  __shared__ unsigned long long sk[8192];
  const int n = blockIdx.x;
  const int tid = threadIdx.x;
  for (int i = tid; i < 8192; i += 1024)
    sk[i] = (i < MCAT)
      ? ((unsigned long long)(~keyd(scat[n * MCAT + i])) << 32) | (unsigned)i
      : ~0ULL;
  __syncthreads();
  for (unsigned k2 = 2; k2 <= 8192; k2 <<= 1)
    for (unsigned j = k2 >> 1; j > 0; j >>= 1) {
      for (int m = 0; m < 8; ++m) {
        unsigned i = (unsigned)tid + (unsigned)m * 1024u;
        unsigned l = i ^ j;
        if (l > i) {
          unsigned long long a = sk[i], bb = sk[l];
          bool up = ((i & k2) == 0);
          if (up ? (a > bb) : (a < bb)) { sk[i] = bb; sk[l] = a; }
        }
      }
      __syncthreads();
    }
  for (int r = tid; r < MCAT; r += 1024) {
    unsigned long long kk = sk[r];
    unsigned pos = (unsigned)kk;
    unsigned d = ~(unsigned)(kk >> 32);
    s_s[n * MCAT + r] = invkey(d);
    b_s[n * MCAT + r] = b[n * MCAT + pos];
    const double* src = ob + ((size_t)n * MCAT + pos) * 4;
    double* dst = ob_s + ((size_t)n * MCAT + r) * 4;
    dst[0] = src[0]; dst[1] = src[1]; dst[2] = src[2]; dst[3] = src[3];
    valid_s[n * MCAT + r] = valid[n * MCAT + pos];
  }
}

// ---------------- K5: suppression bitmask (fp64 IoU, j>i bits) ------------
__global__ __launch_bounds__(256)
void k_mask(const double* __restrict__ ob_s, unsigned long long* __restrict__ mask) {
  const int n = blockIdx.y;
  const int i = blockIdx.x;
  const double* bi = ob_s + ((size_t)n * MCAT + i) * 4;
  const double ix0 = bi[0], iy0 = bi[1], ix1 = bi[2], iy1 = bi[3];
  const double ai = (ix1 - ix0) * (iy1 - iy0);
  const int tid = threadIdx.x;
  for (int j0 = 0; j0 < MCAT; j0 += 256) {
    int j = j0 + tid;
    bool sup = false;
    if (j < MCAT && j > i) {
      const double* bj = ob_s + ((size_t)n * MCAT + j) * 4;
      double jx0 = bj[0], jy0 = bj[1], jx1 = bj[2], jy1 = bj[3];
      double aj = (jx1 - jx0) * (jy1 - jy0);
      double lx = ix0 > jx0 ? ix0 : jx0;
      double ly = iy0 > jy0 ? iy0 : jy0;
      double rx = ix1 < jx1 ? ix1 : jx1;
      double ry = iy1 < jy1 ? iy1 : jy1;
      double wx = rx - lx; wx = wx > 0.0 ? wx : 0.0;
      double wy = ry - ly; wy = wy > 0.0 ? wy : 0.0;
      double inter = wx * wy;
      double iou = inter / (ai + aj - inter + 1e-9);
      sup = iou > 0.7;
    }
    unsigned long long bal = __ballot(sup);
    if ((tid & 63) == 0) {
      int word = (j0 + tid) >> 6;
      if (word < MW) mask[((size_t)n * MCAT + i) * MW + word] = bal;
    }
  }
}

// ---------------- K6: sequential greedy NMS scan + output -----------------
__global__ __launch_bounds__(256)
void k_nms(const unsigned long long* __restrict__ mask,
           const unsigned* __restrict__ valid_s,
           const float* __restrict__ s_s, const float4* __restrict__ b_s,
           float* __restrict__ out) {
  __shared__ unsigned long long rem[MW];
  __shared__ unsigned long long supcc[64];
  __shared__ unsigned long long keepw[MW];
  __shared__ unsigned kpfx[MW], nkpfx[MW];
  __shared__ unsigned sKept;
  const int n = blockIdx.x;
  const int tid = threadIdx.x;
  const unsigned long long* msk = mask + (size_t)n * MCAT * MW;

  for (int w = tid; w < MW; w += 256) {
    unsigned long long r = 0ULL;
    for (int b = 0; b < 64; ++b) {
      int i = w * 64 + b;
      bool rm = (i >= MCAT) || (valid_s[n * MCAT + i] == 0u);
      if (rm) r |= (1ULL << b);
    }
    rem[w] = r;
    keepw[w] = 0ULL;
  }
  __syncthreads();

  for (int c = 0; c < MW; ++c) {
    if (tid < 64) {
      int i = c * 64 + tid;
      supcc[tid] = (i < MCAT) ? msk[(size_t)i * MW + c] : 0ULL;
    }
    __syncthreads();
    unsigned long long r = rem[c], km = 0ULL;
    for (int b = 0; b < 64; ++b) {
      if (!((r >> b) & 1ULL)) { km |= (1ULL << b); r |= supcc[b]; }
    }
    if (tid == 0) { rem[c] = r; keepw[c] = km; }
    __syncthreads();
    for (int w = c + 1 + tid; w < MW; w += 256) {
      unsigned long long acc2 = rem[w];
      unsigned long long k2 = km;
      while (k2) {
        int b = __ffsll((unsigned long long)k2) - 1;
        k2 &= (k2 - 1);
        acc2 |= msk[(size_t)(c * 64 + b) * MW + w];
      }
      rem[w] = acc2;
    }
    __syncthreads();
  }

  if (tid == 0) {
    unsigned ka = 0, na = 0;
    for (int w = 0; w < MW; ++w) {
      kpfx[w] = ka; nkpfx[w] = na;
      unsigned long long range = (w < MW - 1) ? ~0ULL : ((1ULL << 32) - 1ULL); // 4768-4736=32
      ka += (unsigned)__popcll(keepw[w]);
      na += (unsigned)__popcll((~keepw[w]) & range);
    }
    sKept = ka;
  }
  __syncthreads();
  const unsigned keptTotal = sKept;

  for (int i = tid; i < MCAT; i += 256) {
    int w = i >> 6, b = i & 63;
    unsigned long long below = (1ULL << b) - 1ULL;
    bool kept = (keepw[w] >> b) & 1ULL;
    unsigned row;
    if (kept)
      row = kpfx[w] + (unsigned)__popcll(keepw[w] & below);
    else
      row = keptTotal + nkpfx[w] + (unsigned)__popcll((~keepw[w]) & below);
    if (row < 1000u) {
      float4 bb = b_s[n * MCAT + i];
      float sc = kept ? s_s[n * MCAT + i] : -1e4f;
      float* o = out + ((size_t)n * 1000 + row) * 5;
      o[0] = bb.x; o[1] = bb.y; o[2] = bb.z; o[3] = bb.w; o[4] = sc;
    }
  }
}

// ---------------- launch ----------------
extern "C" void kernel_launch(void* const* d_in, const int* in_sizes, int n_in,
                              void* d_out, int out_size, void* d_ws, size_t ws_size,
                              hipStream_t stream) {
  (void)in_sizes; (void)n_in; (void)out_size;
  const float* feats[5] = {(const float*)d_in[0], (const float*)d_in[1],
                           (const float*)d_in[2], (const float*)d_in[3],
                           (const float*)d_in[4]};
  const float* w_conv = (const float*)d_in[5];
  const float* b_conv = (const float*)d_in[6];
  const float* w_obj  = (const float*)d_in[7];
  const float* b_obj  = (const float*)d_in[8];
  const float* w_del  = (const float*)d_in[9];
  const float* b_del  = (const float*)d_in[10];
  float* out = (float*)d_out;

  static const int HS[5]   = {256, 128, 64, 32, 16};
  static const int LOFF[5] = {0, 196608, 245760, 258048, 261120};

  char* p = (char*)d_ws;
  auto alloc = [&](size_t bytes) -> void* {
    void* r = (void*)p;
    p += (bytes + 255) & ~(size_t)255;
    return r;
  };
  float*  t       = (float*)  alloc((size_t)2 * 256 * 256 * 256 * 4); // 134 MB (level-0 size, reused)
  float*  wT      = (float*)  alloc((size_t)2304 * 256 * 4);
  float*  logits  = (float*)  alloc((size_t)NIMG * LTOT * 4);
  float4* deltas  = (float4*) alloc((size_t)NIMG * LTOT * 16);
  float*  scat    = (float*)  alloc((size_t)NIMG * MCAT * 4);
  float4* bout    = (float4*) alloc((size_t)NIMG * MCAT * 16);
  double* obout   = (double*) alloc((size_t)NIMG * MCAT * 32);
  unsigned* valid = (unsigned*)alloc((size_t)NIMG * MCAT * 4);
  float*  s_s     = (float*)  alloc((size_t)NIMG * MCAT * 4);
  float4* b_s     = (float4*) alloc((size_t)NIMG * MCAT * 16);
  double* ob_s    = (double*) alloc((size_t)NIMG * MCAT * 32);
  unsigned* val_s = (unsigned*)alloc((size_t)NIMG * MCAT * 4);
  unsigned long long* mask =
      (unsigned long long*)alloc((size_t)NIMG * MCAT * MW * 8);
  if ((size_t)(p - (char*)d_ws) > ws_size) return; // workspace too small

  k_wT<<<2304, 256, 0, stream>>>(w_conv, wT);

  for (int lvl = 0; lvl < 5; ++lvl) {
    int H = HS[lvl], W = HS[lvl], HW = H * W;
    dim3 g((W + 63) / 64, H / 4, 8);
    k_conv<<<g, 256, 0, stream>>>(feats[lvl], wT, b_conv, t, H, W);
    dim3 g2((HW + 255) / 256, 2);
    k_heads<<<g2, 256, 0, stream>>>(t, w_obj, b_obj, w_del, b_del,
                                    logits, deltas, HW, LOFF[lvl]);
  }

  k_topk<<<10, 1024, 0, stream>>>(logits, deltas, scat, bout, obout, valid);
  k_sort<<<2, 1024, 0, stream>>>(scat, bout, obout, valid, s_s, b_s, ob_s, val_s);
  k_mask<<<dim3(MCAT, 2), 256, 0, stream>>>(ob_s, mask);
  k_nms<<<2, 256, 0, stream>>>(mask, val_s, s_s, b_s, out);
}

// Round 2
// 5011.918 us; speedup vs baseline: 1.3620x; 1.3620x over previous
//
#include <hip/hip_runtime.h>
#include <cstdint>
#include <cstddef>

// ---------------- constants ----------------
static constexpr int NIMG = 2;
static constexpr int CCH  = 256;                  // channels
static constexpr int LTOT = 261888;               // sum H*W*3 over levels
static constexpr int MCAT = 4768;                 // 1000*4 + 768
static constexpr int MW   = 75;                   // ceil(4768/64)
static constexpr double SCALE_CLAMP_D = 4.135166556742356; // ln(1000/16)

// ---------------- key helpers (descending-order monotone uint key) --------
__device__ __forceinline__ unsigned keyd(float f) {
  unsigned u = __float_as_uint(f);
  return (u >> 31) ? ~u : (u | 0x80000000u);
}
__device__ __forceinline__ float invkey(unsigned d) {
  unsigned u = (d & 0x80000000u) ? (d & 0x7FFFFFFFu) : ~d;
  return __uint_as_float(u);
}

// ---------------- K0: transpose conv weights [O][I][3][3] -> [I*9][O] -----
__global__ void k_wT(const float* __restrict__ w, float* __restrict__ wT) {
  int i = blockIdx.x * 256 + threadIdx.x;
  if (i >= 2304 * 256) return;
  int co = i & 255;
  int ct = i >> 8;                 // ci*9 + tap
  wT[ct * 256 + co] = w[co * 2304 + ct];
}

// ---------------- conv3x3 + bias + relu (fp32) body -----------------------
// block tile: 64 couts x (4 rows x 64 cols). 256 threads, each 8co x 8col.
__device__ __forceinline__ void conv_body(
    const float* __restrict__ x, const float* __restrict__ wT,
    const float* __restrict__ bias, float* __restrict__ t,
    int H, int W, int n, int cog, int h0, int w0) {
  __shared__ float xs[8][6][68];
  __shared__ float wsm[8][9][64];
  const int cout0 = cog * 64;
  const int tx = threadIdx.x;
  const int cg8  = tx >> 5;        // 0..7 -> couts cout0+cg8*8 ..+7
  const int rw   = (tx >> 3) & 3;  // row 0..3
  const int colg = tx & 7;         // col group
  const int col0 = colg * 8;

  float acc[8][8];
#pragma unroll
  for (int a = 0; a < 8; ++a)
#pragma unroll
    for (int b = 0; b < 8; ++b) acc[a][b] = 0.f;

  for (int ck = 0; ck < 32; ++ck) {
    // stage x tile (8 cin x 6 rows x 66 cols, zero-padded halo)
    for (int i = tx; i < 8 * 6 * 66; i += 256) {
      int ci = i / 396;
      int r  = (i - ci * 396) / 66;
      int c  = i - ci * 396 - r * 66;
      int gh = h0 - 1 + r, gw = w0 - 1 + c;
      float v = 0.f;
      if ((unsigned)gh < (unsigned)H && (unsigned)gw < (unsigned)W)
        v = x[((size_t)(n * CCH + ck * 8 + ci) * H + gh) * W + gw];
      xs[ci][r][c] = v;
    }
    // stage w tile (8 cin x 9 taps x 64 couts), coalesced from wT
    for (int i = tx; i < 8 * 9 * 64; i += 256) {
      int ci = i / 576;
      int rem = i - ci * 576;
      int tap = rem >> 6;
      int co  = rem & 63;
      wsm[ci][tap][co] = wT[((size_t)(ck * 8 + ci) * 9 + tap) * 256 + cout0 + co];
    }
    __syncthreads();

#pragma unroll
    for (int ci = 0; ci < 8; ++ci) {
      float xr[3][10];
#pragma unroll
      for (int kh = 0; kh < 3; ++kh) {
        const float* p = &xs[ci][rw + kh][col0];
        float4 a0 = *reinterpret_cast<const float4*>(p);
        float4 a1 = *reinterpret_cast<const float4*>(p + 4);
        float2 a2 = *reinterpret_cast<const float2*>(p + 8);
        xr[kh][0]=a0.x; xr[kh][1]=a0.y; xr[kh][2]=a0.z; xr[kh][3]=a0.w;
        xr[kh][4]=a1.x; xr[kh][5]=a1.y; xr[kh][6]=a1.z; xr[kh][7]=a1.w;
        xr[kh][8]=a2.x; xr[kh][9]=a2.y;
      }
#pragma unroll
      for (int kh = 0; kh < 3; ++kh)
#pragma unroll
        for (int kw = 0; kw < 3; ++kw) {
          const float* wp = &wsm[ci][kh * 3 + kw][cg8 * 8];
          float4 wa = *reinterpret_cast<const float4*>(wp);
          float4 wb = *reinterpret_cast<const float4*>(wp + 4);
          float wv[8] = {wa.x, wa.y, wa.z, wa.w, wb.x, wb.y, wb.z, wb.w};
#pragma unroll
          for (int co = 0; co < 8; ++co)
#pragma unroll
            for (int cl = 0; cl < 8; ++cl)
              acc[co][cl] = fmaf(xr[kh][cl + kw], wv[co], acc[co][cl]);
        }
    }
    __syncthreads();
  }

  const int h = h0 + rw;
#pragma unroll
  for (int co = 0; co < 8; ++co) {
    int c = cout0 + cg8 * 8 + co;
    float bv = bias[c];
#pragma unroll
    for (int cl = 0; cl < 8; ++cl) {
      int ww = w0 + col0 + cl;
      if (ww < W) {
        float v = acc[co][cl] + bv;
        t[((size_t)(n * CCH + c) * H + h) * W + ww] = v > 0.f ? v : 0.f;
      }
    }
  }
}

// K1a: level-0 conv (H=W=256), grid (4,64,8)
__global__ __launch_bounds__(256)
void k_conv0(const float* __restrict__ x, const float* __restrict__ wT,
             const float* __restrict__ bias, float* __restrict__ t) {
  int n = blockIdx.z >> 2, cog = blockIdx.z & 3;
  conv_body(x, wT, bias, t, 256, 256, n, cog, blockIdx.y * 4, blockIdx.x * 64);
}

// K1b: fused conv for levels 1-4 (736 blocks, 1D grid, block table)
__global__ __launch_bounds__(256)
void k_conv4(const float* __restrict__ f1, const float* __restrict__ f2,
             const float* __restrict__ f3, const float* __restrict__ f4,
             const float* __restrict__ wT, const float* __restrict__ bias,
             float* __restrict__ t) {
  int b = blockIdx.x;
  const float* x; float* tb; int H, gx, gy, l;
  if (b < 512)      { x = f1; tb = t;            H = 128; gx = 2; gy = 32; l = b; }
  else if (b < 640) { x = f2; tb = t +  8388608; H =  64; gx = 1; gy = 16; l = b - 512; }
  else if (b < 704) { x = f3; tb = t + 10485760; H =  32; gx = 1; gy =  8; l = b - 640; }
  else              { x = f4; tb = t + 11010048; H =  16; gx = 1; gy =  4; l = b - 704; }
  int bx = l % gx;
  int by = (l / gx) % gy;
  int bz = l / (gx * gy);
  int n = bz >> 2, cog = bz & 3;
  conv_body(x, wT, bias, tb, H, H, n, cog, by * 4, bx * 64);
}

// ---------------- 1x1 heads body ------------------------------------------
__device__ __forceinline__ void heads_body(
    const float* __restrict__ t,
    const float* __restrict__ wobj, const float* __restrict__ bobj,
    const float* __restrict__ wdel, const float* __restrict__ bdel,
    float* __restrict__ logits, float4* __restrict__ deltas,
    int HW, int loff, int n, int p) {
  __shared__ float wl[15][256];
  __shared__ float bl[15];
  for (int i = threadIdx.x; i < 15 * 256; i += 256) {
    int o = i >> 8, c = i & 255;
    wl[o][c] = (o < 3) ? wobj[o * 256 + c] : wdel[(o - 3) * 256 + c];
  }
  if (threadIdx.x < 15)
    bl[threadIdx.x] = (threadIdx.x < 3) ? bobj[threadIdx.x] : bdel[threadIdx.x - 3];
  __syncthreads();
  if (p >= HW) return;

  float acc[15];
#pragma unroll
  for (int o = 0; o < 15; ++o) acc[o] = 0.f;
  const float* tp = t + (size_t)n * CCH * HW + p;
  for (int c = 0; c < 256; ++c) {
    float v = tp[(size_t)c * HW];
#pragma unroll
    for (int o = 0; o < 15; ++o) acc[o] = fmaf(v, wl[o][c], acc[o]);
  }
#pragma unroll
  for (int o = 0; o < 15; ++o) acc[o] += bl[o];

  size_t base = (size_t)n * LTOT + loff + (size_t)p * 3;
#pragma unroll
  for (int a = 0; a < 3; ++a) {
    logits[base + a] = acc[a];
    deltas[base + a] = make_float4(acc[3 + a * 4 + 0], acc[3 + a * 4 + 1],
                                   acc[3 + a * 4 + 2], acc[3 + a * 4 + 3]);
  }
}

// K2a: level-0 heads, grid (256, 2)
__global__ __launch_bounds__(256)
void k_heads0(const float* __restrict__ t,
              const float* __restrict__ wobj, const float* __restrict__ bobj,
              const float* __restrict__ wdel, const float* __restrict__ bdel,
              float* __restrict__ logits, float4* __restrict__ deltas) {
  heads_body(t, wobj, bobj, wdel, bdel, logits, deltas,
             65536, 0, blockIdx.y, blockIdx.x * 256 + threadIdx.x);
}

// K2b: fused heads for levels 1-4, grid (85, 2); 256-pixel blocks align with
// level boundaries exactly (64 + 16 + 4 + 1 blocks).
__global__ __launch_bounds__(256)
void k_heads4(const float* __restrict__ t,
              const float* __restrict__ wobj, const float* __restrict__ bobj,
              const float* __restrict__ wdel, const float* __restrict__ bdel,
              float* __restrict__ logits, float4* __restrict__ deltas) {
  int b = blockIdx.x;
  const float* tb; int HW, loff, start;
  if (b < 64)      { tb = t;            HW = 16384; loff = 196608; start = 0;  }
  else if (b < 80) { tb = t +  8388608; HW =  4096; loff = 245760; start = 64; }
  else if (b < 84) { tb = t + 10485760; HW =  1024; loff = 258048; start = 80; }
  else             { tb = t + 11010048; HW =   256; loff = 261120; start = 84; }
  heads_body(tb, wobj, bobj, wdel, bdel, logits, deltas,
             HW, loff, blockIdx.y, (b - start) * 256 + threadIdx.x);
}

// ---------------- K3: per-(n,level) exact stable top-k + box decode -------
__global__ __launch_bounds__(1024)
void k_topk(const float* __restrict__ logits, const float4* __restrict__ deltas,
            float* __restrict__ scat, float4* __restrict__ bout,
            double* __restrict__ obout, unsigned* __restrict__ valid) {
  constexpr int   Hs[5]    = {256, 128, 64, 32, 16};
  constexpr int   strd[5]  = {4, 8, 16, 32, 64};
  constexpr float szs[5]   = {32.f, 64.f, 128.f, 256.f, 512.f};
  constexpr int   loffs[5] = {0, 196608, 245760, 258048, 261120};
  constexpr int   Ms[5]    = {196608, 49152, 12288, 3072, 768};
  constexpr int   ksz[5]   = {1000, 1000, 1000, 1000, 768};
  constexpr int   coffs[5] = {0, 1000, 2000, 3000, 4000};

  __shared__ unsigned hist[2048];
  __shared__ unsigned long long cand[1024];
  __shared__ unsigned tie[1024];
  __shared__ unsigned sB1, sC1, sB2, sC2, sDK, sTN;
  __shared__ unsigned cntG, cntT;

  const int task = blockIdx.x;
  const int n = task / 5, lvl = task % 5;
  const int M = Ms[lvl], K = ksz[lvl], loff = loffs[lvl];
  const float* lg = logits + (size_t)n * LTOT + loff;
  const int tid = threadIdx.x;

  // pass 1: top 11 bits
  for (int i = tid; i < 2048; i += 1024) hist[i] = 0;
  if (tid == 0) { cntG = 0; cntT = 0; }
  __syncthreads();
  for (int i = tid; i < M; i += 1024) atomicAdd(&hist[keyd(lg[i]) >> 21], 1u);
  __syncthreads();
  if (tid == 0) {
    unsigned acc = 0;
    for (int b = 2047; b >= 0; --b) {
      unsigned na = acc + hist[b];
      if (na >= (unsigned)K) { sB1 = (unsigned)b; sC1 = acc; break; }
      acc = na;
    }
  }
  __syncthreads();
  const unsigned B1 = sB1;
  const unsigned rem1 = (unsigned)K - sC1;

  // pass 2: next 11 bits
  for (int i = tid; i < 2048; i += 1024) hist[i] = 0;
  __syncthreads();
  for (int i = tid; i < M; i += 1024) {
    unsigned d = keyd(lg[i]);
    if ((d >> 21) == B1) atomicAdd(&hist[(d >> 10) & 0x7FFu], 1u);
  }
  __syncthreads();
  if (tid == 0) {
    unsigned acc = 0;
    for (int b = 2047; b >= 0; --b) {
      unsigned na = acc + hist[b];
      if (na >= rem1) { sB2 = (unsigned)b; sC2 = acc; break; }
      acc = na;
    }
  }
  __syncthreads();
  const unsigned B2 = sB2;
  const unsigned rem2 = rem1 - sC2;
  const unsigned pfx = (B1 << 11) | B2;

  // pass 3: low 10 bits -> exact k-th key
  for (int i = tid; i < 1024; i += 1024) hist[i] = 0;
  __syncthreads();
  for (int i = tid; i < M; i += 1024) {
    unsigned d = keyd(lg[i]);
    if ((d >> 10) == pfx) atomicAdd(&hist[d & 0x3FFu], 1u);
  }
  __syncthreads();
  if (tid == 0) {
    unsigned acc = 0;
    for (int b = 1023; b >= 0; --b) {
      unsigned na = acc + hist[b];
      if (na >= rem2) { sDK = (pfx << 10) | (unsigned)b; sTN = rem2 - acc; break; }
      acc = na;
    }
  }
  __syncthreads();
  const unsigned dk = sDK;
  const unsigned tneed = sTN;
  const unsigned cg = (unsigned)K - tneed;

  // pass 4: compact strictly-greater + ties
  for (int i = tid; i < M; i += 1024) {
    unsigned d = keyd(lg[i]);
    if (d > dk) {
      unsigned p = atomicAdd(&cntG, 1u);
      cand[p] = ((unsigned long long)(~d) << 32) | (unsigned)i;
    } else if (d == dk) {
      unsigned q = atomicAdd(&cntT, 1u);
      if (q < 1024u) tie[q] = (unsigned)i;
    }
  }
  __syncthreads();
  if (tid == 0) {
    int ct = (int)(cntT < 1024u ? cntT : 1024u);
    for (int a = 1; a < ct; ++a) {            // insertion sort (ascending index)
      unsigned v = tie[a]; int b = a - 1;
      while (b >= 0 && tie[b] > v) { tie[b + 1] = tie[b]; --b; }
      tie[b + 1] = v;
    }
    for (unsigned q = 0; q < tneed; ++q)
      cand[cg + q] = ((unsigned long long)(~dk) << 32) | tie[q];
  }
  __syncthreads();
  if (tid >= K) cand[tid] = ~0ULL;           // pad (tid<1024)
  __syncthreads();

  // bitonic sort 1024 ascending (key = (~d)<<32 | idx  => score desc, idx asc)
  for (unsigned k2 = 2; k2 <= 1024; k2 <<= 1)
    for (unsigned j = k2 >> 1; j > 0; j >>= 1) {
      __syncthreads();
      unsigned i = (unsigned)tid, l = i ^ j;
      if (l > i) {
        unsigned long long a = cand[i], b = cand[l];
        bool up = ((i & k2) == 0);
        if (up ? (a > b) : (a < b)) { cand[i] = b; cand[l] = a; }
      }
    }
  __syncthreads();

  if (tid < K) {
    unsigned long long kk = cand[tid];
    unsigned idx = (unsigned)kk;
    unsigned d = ~(unsigned)(kk >> 32);
    float s = invkey(d);
    int catpos = n * MCAT + coffs[lvl] + tid;
    scat[catpos] = s;

    int a = idx % 3;
    int pix = idx / 3;
    int W = Hs[lvl];
    int hh = pix / W;
    int ww = pix - hh * W;
    float4 d4 = deltas[(size_t)n * LTOT + loff + idx];

    double r  = (a == 0) ? 0.5 : (a == 1 ? 1.0 : 2.0);
    double sz = (double)szs[lvl];
    double cw = sz / sqrt(r);
    double ch = cw * r;
    double cx = (double)(ww * strd[lvl]);
    double cy = (double)(hh * strd[lvl]);
    double dx = (double)d4.x, dy = (double)d4.y;
    double dw = (double)d4.z; if (dw > SCALE_CLAMP_D) dw = SCALE_CLAMP_D;
    double dh = (double)d4.w; if (dh > SCALE_CLAMP_D) dh = SCALE_CLAMP_D;
    double pcx = dx * cw + cx, pcy = dy * ch + cy;
    double pw = exp(dw) * cw,  ph = exp(dh) * ch;
    double x0 = pcx - 0.5 * pw, y0 = pcy - 0.5 * ph;
    double x1 = pcx + 0.5 * pw, y1 = pcy + 0.5 * ph;
    x0 = x0 < 0.0 ? 0.0 : (x0 > 1024.0 ? 1024.0 : x0);
    y0 = y0 < 0.0 ? 0.0 : (y0 > 1024.0 ? 1024.0 : y0);
    x1 = x1 < 0.0 ? 0.0 : (x1 > 1024.0 ? 1024.0 : x1);
    y1 = y1 < 0.0 ? 0.0 : (y1 > 1024.0 ? 1024.0 : y1);
    bool vld = ((x1 - x0) > 0.0) && ((y1 - y0) > 0.0);

    bout[catpos] = make_float4((float)x0, (float)y0, (float)x1, (float)y1);
    double off = (double)lvl * 4096.0;
    double* op = obout + (size_t)catpos * 4;
    op[0] = x0 + off; op[1] = y0 + off; op[2] = x1 + off; op[3] = y1 + off;
    valid[catpos] = vld ? 1u : 0u;
  }
}

// ---------------- K4: per-image stable sort of 4768 candidates ------------
__global__ __launch_bounds__(1024)
void k_sort(const float* __restrict__ scat, const float4* __restrict__ b,
            const double* __restrict__ ob, const unsigned* __restrict__ valid,
            float* __restrict__ s_s, float4* __restrict__ b_s,
            double* __restrict__ ob_s, unsigned* __restrict__ valid_s) {
  __shared__ unsigned long long sk[8192];
  const int n = blockIdx.x;
  const int tid = threadIdx.x;
  for (int i = tid; i < 8192; i += 1024)
    sk[i] = (i < MCAT)
      ? ((unsigned long long)(~keyd(scat[n * MCAT + i])) << 32) | (unsigned)i
      : ~0ULL;
  __syncthreads();
  for (unsigned k2 = 2; k2 <= 8192; k2 <<= 1)
    for (unsigned j = k2 >> 1; j > 0; j >>= 1) {
      for (int m = 0; m < 8; ++m) {
        unsigned i = (unsigned)tid + (unsigned)m * 1024u;
        unsigned l = i ^ j;
        if (l > i) {
          unsigned long long a = sk[i], bb = sk[l];
          bool up = ((i & k2) == 0);
          if (up ? (a > bb) : (a < bb)) { sk[i] = bb; sk[l] = a; }
        }
      }
      __syncthreads();
    }
  for (int r = tid; r < MCAT; r += 1024) {
    unsigned long long kk = sk[r];
    unsigned pos = (unsigned)kk;
    unsigned d = ~(unsigned)(kk >> 32);
    s_s[n * MCAT + r] = invkey(d);
    b_s[n * MCAT + r] = b[n * MCAT + pos];
    const double* src = ob + ((size_t)n * MCAT + pos) * 4;
    double* dst = ob_s + ((size_t)n * MCAT + r) * 4;
    dst[0] = src[0]; dst[1] = src[1]; dst[2] = src[2]; dst[3] = src[3];
    valid_s[n * MCAT + r] = valid[n * MCAT + pos];
  }
}

// ---------------- K5: suppression bitmask (fp64 IoU, j>i bits) ------------
__global__ __launch_bounds__(256)
void k_mask(const double* __restrict__ ob_s, unsigned long long* __restrict__ mask) {
  const int n = blockIdx.y;
  const int i = blockIdx.x;
  const double* bi = ob_s + ((size_t)n * MCAT + i) * 4;
  const double ix0 = bi[0], iy0 = bi[1], ix1 = bi[2], iy1 = bi[3];
  const double ai = (ix1 - ix0) * (iy1 - iy0);
  const int tid = threadIdx.x;
  for (int j0 = 0; j0 < MCAT; j0 += 256) {
    int j = j0 + tid;
    bool sup = false;
    if (j < MCAT && j > i) {
      const double* bj = ob_s + ((size_t)n * MCAT + j) * 4;
      double jx0 = bj[0], jy0 = bj[1], jx1 = bj[2], jy1 = bj[3];
      double aj = (jx1 - jx0) * (jy1 - jy0);
      double lx = ix0 > jx0 ? ix0 : jx0;
      double ly = iy0 > jy0 ? iy0 : jy0;
      double rx = ix1 < jx1 ? ix1 : jx1;
      double ry = iy1 < jy1 ? iy1 : jy1;
      double wx = rx - lx; wx = wx > 0.0 ? wx : 0.0;
      double wy = ry - ly; wy = wy > 0.0 ? wy : 0.0;
      double inter = wx * wy;
      double iou = inter / (ai + aj - inter + 1e-9);
      sup = iou > 0.7;
    }
    unsigned long long bal = __ballot(sup);
    if ((tid & 63) == 0) {
      int word = (j0 + tid) >> 6;
      if (word < MW) mask[((size_t)n * MCAT + i) * MW + word] = bal;
    }
  }
}

// ---------------- K6: greedy NMS scan (parallel rem-update) + output ------
__global__ __launch_bounds__(256)
void k_nms(const unsigned long long* __restrict__ mask,
           const unsigned* __restrict__ valid_s,
           const float* __restrict__ s_s, const float4* __restrict__ b_s,
           float* __restrict__ out) {
  __shared__ unsigned long long rem[MW];     // 1 = invalid or suppressed
  __shared__ unsigned long long supcc[64];
  __shared__ unsigned long long keepw[MW];
  __shared__ int kl[64];                     // kept-bit list within chunk
  __shared__ int snk;
  __shared__ unsigned kpfx[MW], nkpfx[MW];
  __shared__ unsigned sKept;
  const int n = blockIdx.x;
  const int tid = threadIdx.x;
  const unsigned long long* msk = mask + (size_t)n * MCAT * MW;

  for (int w = tid; w < MW; w += 256) {
    unsigned long long r = 0ULL;
    for (int b = 0; b < 64; ++b) {
      int i = w * 64 + b;
      bool rm = (i >= MCAT) || (valid_s[n * MCAT + i] == 0u);
      if (rm) r |= (1ULL << b);
    }
    rem[w] = r;
    keepw[w] = 0ULL;
  }
  __syncthreads();

  for (int c = 0; c < MW; ++c) {
    // stage this chunk's intra-chunk suppression column (word c of rows c*64+b)
    if (tid < 64) {
      int i = c * 64 + tid;
      supcc[tid] = (i < MCAT) ? msk[(size_t)i * MW + c] : 0ULL;
    }
    __syncthreads();
    // serial greedy within chunk (64 bits)
    if (tid == 0) {
      unsigned long long r = rem[c], km = 0ULL;
      int nk = 0;
      for (int b = 0; b < 64; ++b) {
        if (!((r >> b) & 1ULL)) { km |= (1ULL << b); kl[nk++] = b; r |= supcc[b]; }
      }
      rem[c] = r; keepw[c] = km; snk = nk;
    }
    __syncthreads();
    // parallel OR of kept rows into rem[w] for w>c (coalesced, independent)
    const int nk = snk;
    const int nw = MW - 1 - c;
    const int total = nk * nw;
    for (int idx = tid; idx < total; idx += 256) {
      int b = kl[idx / nw];
      int w = c + 1 + (idx % nw);
      unsigned long long v = msk[(size_t)(c * 64 + b) * MW + w];
      if (v) atomicOr(&rem[w], v);
    }
    __syncthreads();
  }

  if (tid == 0) {
    unsigned ka = 0, na = 0;
    for (int w = 0; w < MW; ++w) {
      kpfx[w] = ka; nkpfx[w] = na;
      unsigned long long range = (w < MW - 1) ? ~0ULL : ((1ULL << 32) - 1ULL); // 4768-4736=32
      ka += (unsigned)__popcll(keepw[w]);
      na += (unsigned)__popcll((~keepw[w]) & range);
    }
    sKept = ka;
  }
  __syncthreads();
  const unsigned keptTotal = sKept;

  for (int i = tid; i < MCAT; i += 256) {
    int w = i >> 6, b = i & 63;
    unsigned long long below = (1ULL << b) - 1ULL;
    bool kept = (keepw[w] >> b) & 1ULL;
    unsigned row;
    if (kept)
      row = kpfx[w] + (unsigned)__popcll(keepw[w] & below);
    else
      row = keptTotal + nkpfx[w] + (unsigned)__popcll((~keepw[w]) & below);
    if (row < 1000u) {
      float4 bb = b_s[n * MCAT + i];
      float sc = kept ? s_s[n * MCAT + i] : -1e4f;
      float* o = out + ((size_t)n * 1000 + row) * 5;
      o[0] = bb.x; o[1] = bb.y; o[2] = bb.z; o[3] = bb.w; o[4] = sc;
    }
  }
}

// ---------------- launch ----------------
extern "C" void kernel_launch(void* const* d_in, const int* in_sizes, int n_in,
                              void* d_out, int out_size, void* d_ws, size_t ws_size,
                              hipStream_t stream) {
  (void)in_sizes; (void)n_in; (void)out_size;
  const float* feats[5] = {(const float*)d_in[0], (const float*)d_in[1],
                           (const float*)d_in[2], (const float*)d_in[3],
                           (const float*)d_in[4]};
  const float* w_conv = (const float*)d_in[5];
  const float* b_conv = (const float*)d_in[6];
  const float* w_obj  = (const float*)d_in[7];
  const float* b_obj  = (const float*)d_in[8];
  const float* w_del  = (const float*)d_in[9];
  const float* b_del  = (const float*)d_in[10];
  float* out = (float*)d_out;

  char* p = (char*)d_ws;
  auto alloc = [&](size_t bytes) -> void* {
    void* r = (void*)p;
    p += (bytes + 255) & ~(size_t)255;
    return r;
  };
  float*  t       = (float*)  alloc((size_t)2 * 256 * 256 * 256 * 4); // 134 MB, reused lvl1-4 then lvl0
  float*  wT      = (float*)  alloc((size_t)2304 * 256 * 4);
  float*  logits  = (float*)  alloc((size_t)NIMG * LTOT * 4);
  float4* deltas  = (float4*) alloc((size_t)NIMG * LTOT * 16);
  float*  scat    = (float*)  alloc((size_t)NIMG * MCAT * 4);
  float4* bout    = (float4*) alloc((size_t)NIMG * MCAT * 16);
  double* obout   = (double*) alloc((size_t)NIMG * MCAT * 32);
  unsigned* valid = (unsigned*)alloc((size_t)NIMG * MCAT * 4);
  float*  s_s     = (float*)  alloc((size_t)NIMG * MCAT * 4);
  float4* b_s     = (float4*) alloc((size_t)NIMG * MCAT * 16);
  double* ob_s    = (double*) alloc((size_t)NIMG * MCAT * 32);
  unsigned* val_s = (unsigned*)alloc((size_t)NIMG * MCAT * 4);
  unsigned long long* mask =
      (unsigned long long*)alloc((size_t)NIMG * MCAT * MW * 8);
  if ((size_t)(p - (char*)d_ws) > ws_size) return; // workspace too small

  k_wT<<<2304, 256, 0, stream>>>(w_conv, wT);

  // levels 1-4 fused (uses t[0 .. 11141120)), then their heads consume t
  k_conv4<<<736, 256, 0, stream>>>(feats[1], feats[2], feats[3], feats[4],
                                   wT, b_conv, t);
  k_heads4<<<dim3(85, 2), 256, 0, stream>>>(t, w_obj, b_obj, w_del, b_del,
                                            logits, deltas);
  // level 0 (overwrites t — safe, heads4 already done)
  k_conv0<<<dim3(4, 64, 8), 256, 0, stream>>>(feats[0], wT, b_conv, t);
  k_heads0<<<dim3(256, 2), 256, 0, stream>>>(t, w_obj, b_obj, w_del, b_del,
                                             logits, deltas);

  k_topk<<<10, 1024, 0, stream>>>(logits, deltas, scat, bout, obout, valid);
  k_sort<<<2, 1024, 0, stream>>>(scat, bout, obout, valid, s_s, b_s, ob_s, val_s);
  k_mask<<<dim3(MCAT, 2), 256, 0, stream>>>(ob_s, mask);
  k_nms<<<2, 256, 0, stream>>>(mask, val_s, s_s, b_s, out);
}

// Round 3
// 4946.950 us; speedup vs baseline: 1.3799x; 1.0131x over previous
//
#include <hip/hip_runtime.h>
#include <cstdint>
#include <cstddef>

// ---------------- constants ----------------
static constexpr int NIMG = 2;
static constexpr int CCH  = 256;                  // channels
static constexpr int LTOT = 261888;               // sum H*W*3 over levels
static constexpr int MCAT = 4768;                 // 1000*4 + 768
static constexpr int MW   = 75;                   // ceil(4768/64)
static constexpr double SCALE_CLAMP_D = 4.135166556742356; // ln(1000/16)

// ---------------- key helpers (descending-order monotone uint key) --------
__device__ __forceinline__ unsigned keyd(float f) {
  unsigned u = __float_as_uint(f);
  return (u >> 31) ? ~u : (u | 0x80000000u);
}
__device__ __forceinline__ float invkey(unsigned d) {
  unsigned u = (d & 0x80000000u) ? (d & 0x7FFFFFFFu) : ~d;
  return __uint_as_float(u);
}

// ---------------- K0: transpose conv weights [O][I][3][3] -> [I*9][O] -----
__global__ void k_wT(const float* __restrict__ w, float* __restrict__ wT) {
  int i = blockIdx.x * 256 + threadIdx.x;
  if (i >= 2304 * 256) return;
  int co = i & 255;
  int ct = i >> 8;                 // ci*9 + tap
  wT[ct * 256 + co] = w[co * 2304 + ct];
}

// ---------------- conv3x3 + bias + relu (fp32) body -----------------------
// block tile: 64 couts x (4 rows x 64 cols). 256 threads, each 8co x 8col.
// NOTE: FMA accumulation order (ci,kh,kw,co,cl) is bit-identical to R1/R2 —
// only register liveness changed (one xr row live instead of three).
__device__ __forceinline__ void conv_body(
    const float* __restrict__ x, const float* __restrict__ wT,
    const float* __restrict__ bias, float* __restrict__ t,
    int H, int W, int n, int cog, int h0, int w0) {
  __shared__ float xs[8][6][68];
  __shared__ float wsm[8][9][64];
  const int cout0 = cog * 64;
  const int tx = threadIdx.x;
  const int cg8  = tx >> 5;        // 0..7 -> couts cout0+cg8*8 ..+7
  const int rw   = (tx >> 3) & 3;  // row 0..3
  const int colg = tx & 7;         // col group
  const int col0 = colg * 8;

  float acc[8][8];
#pragma unroll
  for (int a = 0; a < 8; ++a)
#pragma unroll
    for (int b = 0; b < 8; ++b) acc[a][b] = 0.f;

  for (int ck = 0; ck < 32; ++ck) {
    // stage x tile (8 cin x 6 rows x 66 cols, zero-padded halo)
    for (int i = tx; i < 8 * 6 * 66; i += 256) {
      int ci = i / 396;
      int r  = (i - ci * 396) / 66;
      int c  = i - ci * 396 - r * 66;
      int gh = h0 - 1 + r, gw = w0 - 1 + c;
      float v = 0.f;
      if ((unsigned)gh < (unsigned)H && (unsigned)gw < (unsigned)W)
        v = x[((size_t)(n * CCH + ck * 8 + ci) * H + gh) * W + gw];
      xs[ci][r][c] = v;
    }
    // stage w tile (8 cin x 9 taps x 64 couts), coalesced from wT
    for (int i = tx; i < 8 * 9 * 64; i += 256) {
      int ci = i / 576;
      int rem = i - ci * 576;
      int tap = rem >> 6;
      int co  = rem & 63;
      wsm[ci][tap][co] = wT[((size_t)(ck * 8 + ci) * 9 + tap) * 256 + cout0 + co];
    }
    __syncthreads();

#pragma unroll
    for (int ci = 0; ci < 8; ++ci) {
#pragma unroll
      for (int kh = 0; kh < 3; ++kh) {
        const float* p = &xs[ci][rw + kh][col0];
        float4 a0 = *reinterpret_cast<const float4*>(p);
        float4 a1 = *reinterpret_cast<const float4*>(p + 4);
        float2 a2 = *reinterpret_cast<const float2*>(p + 8);
        float xr[10] = {a0.x, a0.y, a0.z, a0.w, a1.x, a1.y, a1.z, a1.w, a2.x, a2.y};
#pragma unroll
        for (int kw = 0; kw < 3; ++kw) {
          const float* wp = &wsm[ci][kh * 3 + kw][cg8 * 8];
          float4 wa = *reinterpret_cast<const float4*>(wp);
          float4 wb = *reinterpret_cast<const float4*>(wp + 4);
          float wv[8] = {wa.x, wa.y, wa.z, wa.w, wb.x, wb.y, wb.z, wb.w};
#pragma unroll
          for (int co = 0; co < 8; ++co)
#pragma unroll
            for (int cl = 0; cl < 8; ++cl)
              acc[co][cl] = fmaf(xr[cl + kw], wv[co], acc[co][cl]);
        }
      }
    }
    __syncthreads();
  }

  const int h = h0 + rw;
#pragma unroll
  for (int co = 0; co < 8; ++co) {
    int c = cout0 + cg8 * 8 + co;
    float bv = bias[c];
#pragma unroll
    for (int cl = 0; cl < 8; ++cl) {
      int ww = w0 + col0 + cl;
      if (ww < W) {
        float v = acc[co][cl] + bv;
        t[((size_t)(n * CCH + c) * H + h) * W + ww] = v > 0.f ? v : 0.f;
      }
    }
  }
}

// K1a: level-0 conv (H=W=256), grid (4,64,8)
// launch_bounds(256,2): 2 waves/EU -> up to 256 VGPR/thread; kills the
// AGPR-copy spills the default target forced (VGPR_Count was 100 @ 58 TF).
__global__ __launch_bounds__(256, 2)
void k_conv0(const float* __restrict__ x, const float* __restrict__ wT,
             const float* __restrict__ bias, float* __restrict__ t) {
  int n = blockIdx.z >> 2, cog = blockIdx.z & 3;
  conv_body(x, wT, bias, t, 256, 256, n, cog, blockIdx.y * 4, blockIdx.x * 64);
}

// K1b: fused conv for levels 1-4 (736 blocks, 1D grid, block table)
__global__ __launch_bounds__(256, 2)
void k_conv4(const float* __restrict__ f1, const float* __restrict__ f2,
             const float* __restrict__ f3, const float* __restrict__ f4,
             const float* __restrict__ wT, const float* __restrict__ bias,
             float* __restrict__ t) {
  int b = blockIdx.x;
  const float* x; float* tb; int H, gx, gy, l;
  if (b < 512)      { x = f1; tb = t;            H = 128; gx = 2; gy = 32; l = b; }
  else if (b < 640) { x = f2; tb = t +  8388608; H =  64; gx = 1; gy = 16; l = b - 512; }
  else if (b < 704) { x = f3; tb = t + 10485760; H =  32; gx = 1; gy =  8; l = b - 640; }
  else              { x = f4; tb = t + 11010048; H =  16; gx = 1; gy =  4; l = b - 704; }
  int bx = l % gx;
  int by = (l / gx) % gy;
  int bz = l / (gx * gy);
  int n = bz >> 2, cog = bz & 3;
  conv_body(x, wT, bias, tb, H, H, n, cog, by * 4, bx * 64);
}

// ---------------- 1x1 heads body (4 pixels/thread, float4 loads) ----------
__device__ __forceinline__ void heads_body(
    const float* __restrict__ t,
    const float* __restrict__ wobj, const float* __restrict__ bobj,
    const float* __restrict__ wdel, const float* __restrict__ bdel,
    float* __restrict__ logits, float4* __restrict__ deltas,
    int HW, int loff, int n, int p0) {
  __shared__ float wl[15][256];
  __shared__ float bl[15];
  for (int i = threadIdx.x; i < 15 * 256; i += 256) {
    int o = i >> 8, c = i & 255;
    wl[o][c] = (o < 3) ? wobj[o * 256 + c] : wdel[(o - 3) * 256 + c];
  }
  if (threadIdx.x < 15)
    bl[threadIdx.x] = (threadIdx.x < 3) ? bobj[threadIdx.x] : bdel[threadIdx.x - 3];
  __syncthreads();
  if (p0 >= HW) return;

  float4 acc[15];
#pragma unroll
  for (int o = 0; o < 15; ++o) acc[o] = make_float4(0.f, 0.f, 0.f, 0.f);
  const float* tp = t + (size_t)n * CCH * HW + p0;
  for (int c = 0; c < 256; ++c) {
    float4 v = *reinterpret_cast<const float4*>(tp + (size_t)c * HW);
#pragma unroll
    for (int o = 0; o < 15; ++o) {
      float wv = wl[o][c];
      acc[o].x = fmaf(v.x, wv, acc[o].x);
      acc[o].y = fmaf(v.y, wv, acc[o].y);
      acc[o].z = fmaf(v.z, wv, acc[o].z);
      acc[o].w = fmaf(v.w, wv, acc[o].w);
    }
  }
#pragma unroll
  for (int o = 0; o < 15; ++o) {
    float bv = bl[o];
    acc[o].x += bv; acc[o].y += bv; acc[o].z += bv; acc[o].w += bv;
  }

  const float* af = reinterpret_cast<const float*>(acc); // af[o*4+i] = out o, pixel p0+i
  size_t base = (size_t)n * LTOT + loff + (size_t)p0 * 3;
#pragma unroll
  for (int i2 = 0; i2 < 4; ++i2) {
#pragma unroll
    for (int a = 0; a < 3; ++a) {
      logits[base + i2 * 3 + a] = af[a * 4 + i2];
      deltas[base + i2 * 3 + a] =
          make_float4(af[(3 + a * 4 + 0) * 4 + i2], af[(3 + a * 4 + 1) * 4 + i2],
                      af[(3 + a * 4 + 2) * 4 + i2], af[(3 + a * 4 + 3) * 4 + i2]);
    }
  }
}

// K2a: level-0 heads, grid (64, 2) — 1024 px/block
__global__ __launch_bounds__(256)
void k_heads0(const float* __restrict__ t,
              const float* __restrict__ wobj, const float* __restrict__ bobj,
              const float* __restrict__ wdel, const float* __restrict__ bdel,
              float* __restrict__ logits, float4* __restrict__ deltas) {
  heads_body(t, wobj, bobj, wdel, bdel, logits, deltas,
             65536, 0, blockIdx.y, (blockIdx.x * 256 + threadIdx.x) * 4);
}

// K2b: fused heads for levels 1-4, grid (22, 2); 1024 px/block.
__global__ __launch_bounds__(256)
void k_heads4(const float* __restrict__ t,
              const float* __restrict__ wobj, const float* __restrict__ bobj,
              const float* __restrict__ wdel, const float* __restrict__ bdel,
              float* __restrict__ logits, float4* __restrict__ deltas) {
  int b = blockIdx.x;
  const float* tb; int HW, loff, start;
  if (b < 16)      { tb = t;            HW = 16384; loff = 196608; start = 0;  }
  else if (b < 20) { tb = t +  8388608; HW =  4096; loff = 245760; start = 16; }
  else if (b < 21) { tb = t + 10485760; HW =  1024; loff = 258048; start = 20; }
  else             { tb = t + 11010048; HW =   256; loff = 261120; start = 21; }
  heads_body(tb, wobj, bobj, wdel, bdel, logits, deltas,
             HW, loff, blockIdx.y, ((b - start) * 256 + threadIdx.x) * 4);
}

// ---------------- K3: per-(n,level) exact stable top-k + box decode -------
__global__ __launch_bounds__(1024)
void k_topk(const float* __restrict__ logits, const float4* __restrict__ deltas,
            float* __restrict__ scat, float4* __restrict__ bout,
            double* __restrict__ obout, unsigned* __restrict__ valid) {
  constexpr int   Hs[5]    = {256, 128, 64, 32, 16};
  constexpr int   strd[5]  = {4, 8, 16, 32, 64};
  constexpr float szs[5]   = {32.f, 64.f, 128.f, 256.f, 512.f};
  constexpr int   loffs[5] = {0, 196608, 245760, 258048, 261120};
  constexpr int   Ms[5]    = {196608, 49152, 12288, 3072, 768};
  constexpr int   ksz[5]   = {1000, 1000, 1000, 1000, 768};
  constexpr int   coffs[5] = {0, 1000, 2000, 3000, 4000};

  __shared__ unsigned hist[2048];
  __shared__ unsigned long long cand[1024];
  __shared__ unsigned tie[1024];
  __shared__ unsigned sB1, sC1, sB2, sC2, sDK, sTN;
  __shared__ unsigned cntG, cntT;

  const int task = blockIdx.x;
  const int n = task / 5, lvl = task % 5;
  const int M = Ms[lvl], K = ksz[lvl], loff = loffs[lvl];
  const float* lg = logits + (size_t)n * LTOT + loff;
  const int tid = threadIdx.x;

  // pass 1: top 11 bits
  for (int i = tid; i < 2048; i += 1024) hist[i] = 0;
  if (tid == 0) { cntG = 0; cntT = 0; }
  __syncthreads();
  for (int i = tid; i < M; i += 1024) atomicAdd(&hist[keyd(lg[i]) >> 21], 1u);
  __syncthreads();
  if (tid == 0) {
    unsigned acc = 0;
    for (int b = 2047; b >= 0; --b) {
      unsigned na = acc + hist[b];
      if (na >= (unsigned)K) { sB1 = (unsigned)b; sC1 = acc; break; }
      acc = na;
    }
  }
  __syncthreads();
  const unsigned B1 = sB1;
  const unsigned rem1 = (unsigned)K - sC1;

  // pass 2: next 11 bits
  for (int i = tid; i < 2048; i += 1024) hist[i] = 0;
  __syncthreads();
  for (int i = tid; i < M; i += 1024) {
    unsigned d = keyd(lg[i]);
    if ((d >> 21) == B1) atomicAdd(&hist[(d >> 10) & 0x7FFu], 1u);
  }
  __syncthreads();
  if (tid == 0) {
    unsigned acc = 0;
    for (int b = 2047; b >= 0; --b) {
      unsigned na = acc + hist[b];
      if (na >= rem1) { sB2 = (unsigned)b; sC2 = acc; break; }
      acc = na;
    }
  }
  __syncthreads();
  const unsigned B2 = sB2;
  const unsigned rem2 = rem1 - sC2;
  const unsigned pfx = (B1 << 11) | B2;

  // pass 3: low 10 bits -> exact k-th key
  for (int i = tid; i < 1024; i += 1024) hist[i] = 0;
  __syncthreads();
  for (int i = tid; i < M; i += 1024) {
    unsigned d = keyd(lg[i]);
    if ((d >> 10) == pfx) atomicAdd(&hist[d & 0x3FFu], 1u);
  }
  __syncthreads();
  if (tid == 0) {
    unsigned acc = 0;
    for (int b = 1023; b >= 0; --b) {
      unsigned na = acc + hist[b];
      if (na >= rem2) { sDK = (pfx << 10) | (unsigned)b; sTN = rem2 - acc; break; }
      acc = na;
    }
  }
  __syncthreads();
  const unsigned dk = sDK;
  const unsigned tneed = sTN;
  const unsigned cg = (unsigned)K - tneed;

  // pass 4: compact strictly-greater + ties
  for (int i = tid; i < M; i += 1024) {
    unsigned d = keyd(lg[i]);
    if (d > dk) {
      unsigned p = atomicAdd(&cntG, 1u);
      cand[p] = ((unsigned long long)(~d) << 32) | (unsigned)i;
    } else if (d == dk) {
      unsigned q = atomicAdd(&cntT, 1u);
      if (q < 1024u) tie[q] = (unsigned)i;
    }
  }
  __syncthreads();
  if (tid == 0) {
    int ct = (int)(cntT < 1024u ? cntT : 1024u);
    for (int a = 1; a < ct; ++a) {            // insertion sort (ascending index)
      unsigned v = tie[a]; int b = a - 1;
      while (b >= 0 && tie[b] > v) { tie[b + 1] = tie[b]; --b; }
      tie[b + 1] = v;
    }
    for (unsigned q = 0; q < tneed; ++q)
      cand[cg + q] = ((unsigned long long)(~dk) << 32) | tie[q];
  }
  __syncthreads();
  if (tid >= K) cand[tid] = ~0ULL;           // pad (tid<1024)
  __syncthreads();

  // bitonic sort 1024 ascending (key = (~d)<<32 | idx  => score desc, idx asc)
  for (unsigned k2 = 2; k2 <= 1024; k2 <<= 1)
    for (unsigned j = k2 >> 1; j > 0; j >>= 1) {
      __syncthreads();
      unsigned i = (unsigned)tid, l = i ^ j;
      if (l > i) {
        unsigned long long a = cand[i], b = cand[l];
        bool up = ((i & k2) == 0);
        if (up ? (a > b) : (a < b)) { cand[i] = b; cand[l] = a; }
      }
    }
  __syncthreads();

  if (tid < K) {
    unsigned long long kk = cand[tid];
    unsigned idx = (unsigned)kk;
    unsigned d = ~(unsigned)(kk >> 32);
    float s = invkey(d);
    int catpos = n * MCAT + coffs[lvl] + tid;
    scat[catpos] = s;

    int a = idx % 3;
    int pix = idx / 3;
    int W = Hs[lvl];
    int hh = pix / W;
    int ww = pix - hh * W;
    float4 d4 = deltas[(size_t)n * LTOT + loff + idx];

    double r  = (a == 0) ? 0.5 : (a == 1 ? 1.0 : 2.0);
    double sz = (double)szs[lvl];
    double cw = sz / sqrt(r);
    double ch = cw * r;
    double cx = (double)(ww * strd[lvl]);
    double cy = (double)(hh * strd[lvl]);
    double dx = (double)d4.x, dy = (double)d4.y;
    double dw = (double)d4.z; if (dw > SCALE_CLAMP_D) dw = SCALE_CLAMP_D;
    double dh = (double)d4.w; if (dh > SCALE_CLAMP_D) dh = SCALE_CLAMP_D;
    double pcx = dx * cw + cx, pcy = dy * ch + cy;
    double pw = exp(dw) * cw,  ph = exp(dh) * ch;
    double x0 = pcx - 0.5 * pw, y0 = pcy - 0.5 * ph;
    double x1 = pcx + 0.5 * pw, y1 = pcy + 0.5 * ph;
    x0 = x0 < 0.0 ? 0.0 : (x0 > 1024.0 ? 1024.0 : x0);
    y0 = y0 < 0.0 ? 0.0 : (y0 > 1024.0 ? 1024.0 : y0);
    x1 = x1 < 0.0 ? 0.0 : (x1 > 1024.0 ? 1024.0 : x1);
    y1 = y1 < 0.0 ? 0.0 : (y1 > 1024.0 ? 1024.0 : y1);
    bool vld = ((x1 - x0) > 0.0) && ((y1 - y0) > 0.0);

    bout[catpos] = make_float4((float)x0, (float)y0, (float)x1, (float)y1);
    double off = (double)lvl * 4096.0;
    double* op = obout + (size_t)catpos * 4;
    op[0] = x0 + off; op[1] = y0 + off; op[2] = x1 + off; op[3] = y1 + off;
    valid[catpos] = vld ? 1u : 0u;
  }
}

// ---------------- K4: per-image stable sort of 4768 candidates ------------
__global__ __launch_bounds__(1024)
void k_sort(const float* __restrict__ scat, const float4* __restrict__ b,
            const double* __restrict__ ob, const unsigned* __restrict__ valid,
            float* __restrict__ s_s, float4* __restrict__ b_s,
            double* __restrict__ ob_s, unsigned* __restrict__ valid_s) {
  __shared__ unsigned long long sk[8192];
  const int n = blockIdx.x;
  const int tid = threadIdx.x;
  for (int i = tid; i < 8192; i += 1024)
    sk[i] = (i < MCAT)
      ? ((unsigned long long)(~keyd(scat[n * MCAT + i])) << 32) | (unsigned)i
      : ~0ULL;
  __syncthreads();
  for (unsigned k2 = 2; k2 <= 8192; k2 <<= 1)
    for (unsigned j = k2 >> 1; j > 0; j >>= 1) {
      for (int m = 0; m < 8; ++m) {
        unsigned i = (unsigned)tid + (unsigned)m * 1024u;
        unsigned l = i ^ j;
        if (l > i) {
          unsigned long long a = sk[i], bb = sk[l];
          bool up = ((i & k2) == 0);
          if (up ? (a > bb) : (a < bb)) { sk[i] = bb; sk[l] = a; }
        }
      }
      __syncthreads();
    }
  for (int r = tid; r < MCAT; r += 1024) {
    unsigned long long kk = sk[r];
    unsigned pos = (unsigned)kk;
    unsigned d = ~(unsigned)(kk >> 32);
    s_s[n * MCAT + r] = invkey(d);
    b_s[n * MCAT + r] = b[n * MCAT + pos];
    const double* src = ob + ((size_t)n * MCAT + pos) * 4;
    double* dst = ob_s + ((size_t)n * MCAT + r) * 4;
    dst[0] = src[0]; dst[1] = src[1]; dst[2] = src[2]; dst[3] = src[3];
    valid_s[n * MCAT + r] = valid[n * MCAT + pos];
  }
}

// ---------------- K5: suppression bitmask (fp64 IoU, j>i bits) ------------
__global__ __launch_bounds__(256)
void k_mask(const double* __restrict__ ob_s, unsigned long long* __restrict__ mask) {
  const int n = blockIdx.y;
  const int i = blockIdx.x;
  const double* bi = ob_s + ((size_t)n * MCAT + i) * 4;
  const double ix0 = bi[0], iy0 = bi[1], ix1 = bi[2], iy1 = bi[3];
  const double ai = (ix1 - ix0) * (iy1 - iy0);
  const int tid = threadIdx.x;
  for (int j0 = 0; j0 < MCAT; j0 += 256) {
    int j = j0 + tid;
    bool sup = false;
    if (j < MCAT && j > i) {
      const double* bj = ob_s + ((size_t)n * MCAT + j) * 4;
      double jx0 = bj[0], jy0 = bj[1], jx1 = bj[2], jy1 = bj[3];
      double aj = (jx1 - jx0) * (jy1 - jy0);
      double lx = ix0 > jx0 ? ix0 : jx0;
      double ly = iy0 > jy0 ? iy0 : jy0;
      double rx = ix1 < jx1 ? ix1 : jx1;
      double ry = iy1 < jy1 ? iy1 : jy1;
      double wx = rx - lx; wx = wx > 0.0 ? wx : 0.0;
      double wy = ry - ly; wy = wy > 0.0 ? wy : 0.0;
      double inter = wx * wy;
      double iou = inter / (ai + aj - inter + 1e-9);
      sup = iou > 0.7;
    }
    unsigned long long bal = __ballot(sup);
    if ((tid & 63) == 0) {
      int word = (j0 + tid) >> 6;
      if (word < MW) mask[((size_t)n * MCAT + i) * MW + word] = bal;
    }
  }
}

// ---------------- K6: greedy NMS scan (parallel rem-update) + output ------
__global__ __launch_bounds__(256)
void k_nms(const unsigned long long* __restrict__ mask,
           const unsigned* __restrict__ valid_s,
           const float* __restrict__ s_s, const float4* __restrict__ b_s,
           float* __restrict__ out) {
  __shared__ unsigned long long rem[MW];     // 1 = invalid or suppressed
  __shared__ unsigned long long supcc[64];
  __shared__ unsigned long long keepw[MW];
  __shared__ int kl[64];                     // kept-bit list within chunk
  __shared__ int snk;
  __shared__ unsigned kpfx[MW], nkpfx[MW];
  __shared__ unsigned sKept;
  const int n = blockIdx.x;
  const int tid = threadIdx.x;
  const unsigned long long* msk = mask + (size_t)n * MCAT * MW;

  for (int w = tid; w < MW; w += 256) {
    unsigned long long r = 0ULL;
    for (int b = 0; b < 64; ++b) {
      int i = w * 64 + b;
      bool rm = (i >= MCAT) || (valid_s[n * MCAT + i] == 0u);
      if (rm) r |= (1ULL << b);
    }
    rem[w] = r;
    keepw[w] = 0ULL;
  }
  __syncthreads();

  for (int c = 0; c < MW; ++c) {
    // stage this chunk's intra-chunk suppression column (word c of rows c*64+b)
    if (tid < 64) {
      int i = c * 64 + tid;
      supcc[tid] = (i < MCAT) ? msk[(size_t)i * MW + c] : 0ULL;
    }
    __syncthreads();
    // serial greedy within chunk (64 bits)
    if (tid == 0) {
      unsigned long long r = rem[c], km = 0ULL;
      int nk = 0;
      for (int b = 0; b < 64; ++b) {
        if (!((r >> b) & 1ULL)) { km |= (1ULL << b); kl[nk++] = b; r |= supcc[b]; }
      }
      rem[c] = r; keepw[c] = km; snk = nk;
    }
    __syncthreads();
    // parallel OR of kept rows into rem[w] for w>c (coalesced, independent)
    const int nk = snk;
    const int nw = MW - 1 - c;
    const int total = nk * nw;
    for (int idx = tid; idx < total; idx += 256) {
      int b = kl[idx / nw];
      int w = c + 1 + (idx % nw);
      unsigned long long v = msk[(size_t)(c * 64 + b) * MW + w];
      if (v) atomicOr(&rem[w], v);
    }
    __syncthreads();
  }

  if (tid == 0) {
    unsigned ka = 0, na = 0;
    for (int w = 0; w < MW; ++w) {
      kpfx[w] = ka; nkpfx[w] = na;
      unsigned long long range = (w < MW - 1) ? ~0ULL : ((1ULL << 32) - 1ULL); // 4768-4736=32
      ka += (unsigned)__popcll(keepw[w]);
      na += (unsigned)__popcll((~keepw[w]) & range);
    }
    sKept = ka;
  }
  __syncthreads();
  const unsigned keptTotal = sKept;

  for (int i = tid; i < MCAT; i += 256) {
    int w = i >> 6, b = i & 63;
    unsigned long long below = (1ULL << b) - 1ULL;
    bool kept = (keepw[w] >> b) & 1ULL;
    unsigned row;
    if (kept)
      row = kpfx[w] + (unsigned)__popcll(keepw[w] & below);
    else
      row = keptTotal + nkpfx[w] + (unsigned)__popcll((~keepw[w]) & below);
    if (row < 1000u) {
      float4 bb = b_s[n * MCAT + i];
      float sc = kept ? s_s[n * MCAT + i] : -1e4f;
      float* o = out + ((size_t)n * 1000 + row) * 5;
      o[0] = bb.x; o[1] = bb.y; o[2] = bb.z; o[3] = bb.w; o[4] = sc;
    }
  }
}

// ---------------- launch ----------------
extern "C" void kernel_launch(void* const* d_in, const int* in_sizes, int n_in,
                              void* d_out, int out_size, void* d_ws, size_t ws_size,
                              hipStream_t stream) {
  (void)in_sizes; (void)n_in; (void)out_size;
  const float* feats[5] = {(const float*)d_in[0], (const float*)d_in[1],
                           (const float*)d_in[2], (const float*)d_in[3],
                           (const float*)d_in[4]};
  const float* w_conv = (const float*)d_in[5];
  const float* b_conv = (const float*)d_in[6];
  const float* w_obj  = (const float*)d_in[7];
  const float* b_obj  = (const float*)d_in[8];
  const float* w_del  = (const float*)d_in[9];
  const float* b_del  = (const float*)d_in[10];
  float* out = (float*)d_out;

  char* p = (char*)d_ws;
  auto alloc = [&](size_t bytes) -> void* {
    void* r = (void*)p;
    p += (bytes + 255) & ~(size_t)255;
    return r;
  };
  float*  t       = (float*)  alloc((size_t)2 * 256 * 256 * 256 * 4); // 134 MB, reused lvl1-4 then lvl0
  float*  wT      = (float*)  alloc((size_t)2304 * 256 * 4);
  float*  logits  = (float*)  alloc((size_t)NIMG * LTOT * 4);
  float4* deltas  = (float4*) alloc((size_t)NIMG * LTOT * 16);
  float*  scat    = (float*)  alloc((size_t)NIMG * MCAT * 4);
  float4* bout    = (float4*) alloc((size_t)NIMG * MCAT * 16);
  double* obout   = (double*) alloc((size_t)NIMG * MCAT * 32);
  unsigned* valid = (unsigned*)alloc((size_t)NIMG * MCAT * 4);
  float*  s_s     = (float*)  alloc((size_t)NIMG * MCAT * 4);
  float4* b_s     = (float4*) alloc((size_t)NIMG * MCAT * 16);
  double* ob_s    = (double*) alloc((size_t)NIMG * MCAT * 32);
  unsigned* val_s = (unsigned*)alloc((size_t)NIMG * MCAT * 4);
  unsigned long long* mask =
      (unsigned long long*)alloc((size_t)NIMG * MCAT * MW * 8);
  if ((size_t)(p - (char*)d_ws) > ws_size) return; // workspace too small

  k_wT<<<2304, 256, 0, stream>>>(w_conv, wT);

  // levels 1-4 fused (uses t[0 .. 11141120)), then their heads consume t
  k_conv4<<<736, 256, 0, stream>>>(feats[1], feats[2], feats[3], feats[4],
                                   wT, b_conv, t);
  k_heads4<<<dim3(22, 2), 256, 0, stream>>>(t, w_obj, b_obj, w_del, b_del,
                                            logits, deltas);
  // level 0 (overwrites t — safe, heads4 already done)
  k_conv0<<<dim3(4, 64, 8), 256, 0, stream>>>(feats[0], wT, b_conv, t);
  k_heads0<<<dim3(64, 2), 256, 0, stream>>>(t, w_obj, b_obj, w_del, b_del,
                                            logits, deltas);

  k_topk<<<10, 1024, 0, stream>>>(logits, deltas, scat, bout, obout, valid);
  k_sort<<<2, 1024, 0, stream>>>(scat, bout, obout, valid, s_s, b_s, ob_s, val_s);
  k_mask<<<dim3(MCAT, 2), 256, 0, stream>>>(ob_s, mask);
  k_nms<<<2, 256, 0, stream>>>(mask, val_s, s_s, b_s, out);
}

// Round 5
// 4543.004 us; speedup vs baseline: 1.5026x; 1.0889x over previous
//
#include <hip/hip_runtime.h>
#include <cstdint>
#include <cstddef>

// ---------------- constants ----------------
static constexpr int NIMG = 2;
static constexpr int CCH  = 256;                  // channels
static constexpr int LTOT = 261888;               // sum H*W*3 over levels
static constexpr int MCAT = 4768;                 // 1000*4 + 768
static constexpr int MW   = 75;                   // ceil(4768/64)
static constexpr double SCALE_CLAMP_D = 4.135166556742356; // ln(1000/16)

// BITWISE CONSTRAINT (learned R4): the harness np-reference is fp32 and our
// conv matched it bitwise in R1-R3 (absmax exactly 0.0). Sorted-score spacing
// (~7.7e-4) makes any logit error >~1e-7 flip ranks -> huge absmax. So the
// conv MUST remain sequential fp32 FMA in (cin ascending, kh, kw) order.
// No MFMA, no K-splitting, no reassociation. Optimize resources only.

// ---------------- key helpers (descending-order monotone uint key) --------
__device__ __forceinline__ unsigned keyd(float f) {
  unsigned u = __float_as_uint(f);
  return (u >> 31) ? ~u : (u | 0x80000000u);
}
__device__ __forceinline__ float invkey(unsigned d) {
  unsigned u = (d & 0x80000000u) ? (d & 0x7FFFFFFFu) : ~d;
  return __uint_as_float(u);
}

// ---------------- K0: transpose conv weights [O][I][3][3] -> [I*9][O] -----
__global__ void k_wT(const float* __restrict__ w, float* __restrict__ wT) {
  int i = blockIdx.x * 256 + threadIdx.x;
  if (i >= 2304 * 256) return;
  int co = i & 255;
  int ct = i >> 8;                 // ci*9 + tap
  wT[ct * 256 + co] = w[co * 2304 + ct];
}

// ---------------- conv3x3 + bias + relu (fp32, bitwise-pinned) ------------
// Block tile: 64 couts x (4 rows x 64 cols). 256 threads, each 4co x 16px.
// acc = 64 regs (fits in VGPRs without AGPR spill -> full-rate v_fmac);
// wv = single b128 broadcast (16-lane same-address); xr = 18 aligned floats.
__device__ __forceinline__ void conv_body(
    const float* __restrict__ x, const float* __restrict__ wT,
    const float* __restrict__ bias, float* __restrict__ t,
    int H, int W, int n, int cog, int h0, int w0) {
  __shared__ __align__(16) float xs[8][6][76];   // stride 76: 16B-aligned rows, bank-spread
  __shared__ __align__(16) float wsm[8][9][64];
  const int cout0 = cog * 64;
  const int tx = threadIdx.x;
  const int cog4 = tx >> 4;        // 0..15 -> couts cout0+cog4*4 ..+3
  const int pxg  = tx & 15;
  const int r2   = pxg >> 2;       // row 0..3
  const int col0 = (pxg & 3) * 16; // col group (16 px per thread)

  float acc[4][16];
#pragma unroll
  for (int a = 0; a < 4; ++a)
#pragma unroll
    for (int b = 0; b < 16; ++b) acc[a][b] = 0.f;

  for (int ck = 0; ck < 32; ++ck) {
    // stage x: 8 cin x 6 rows x 66 cols halo (cols 66..75 unused, never read)
#pragma unroll
    for (int ci = 0; ci < 8; ++ci) {
      const float* xc = x + (size_t)(n * CCH + ck * 8 + ci) * H * W;
      for (int e = tx; e < 396; e += 256) {
        int r = e / 66, c = e - r * 66;
        int gh = h0 - 1 + r, gw = w0 - 1 + c;
        float v = 0.f;
        if ((unsigned)gh < (unsigned)H && (unsigned)gw < (unsigned)W)
          v = xc[gh * W + gw];
        xs[ci][r][c] = v;
      }
    }
    // stage w: 8 cin x 9 taps x 64 couts (pow2-friendly index math)
#pragma unroll
    for (int ci = 0; ci < 8; ++ci) {
      for (int e = tx; e < 576; e += 256) {
        int tap = e >> 6, co = e & 63;
        wsm[ci][tap][co] = wT[((size_t)(ck * 8 + ci) * 9 + tap) * 256 + cout0 + co];
      }
    }
    __syncthreads();

#pragma unroll
    for (int ci = 0; ci < 8; ++ci) {
#pragma unroll
      for (int kh = 0; kh < 3; ++kh) {
        const float* p = &xs[ci][r2 + kh][col0];
        float4 a0 = *reinterpret_cast<const float4*>(p);
        float4 a1 = *reinterpret_cast<const float4*>(p + 4);
        float4 a2 = *reinterpret_cast<const float4*>(p + 8);
        float4 a3 = *reinterpret_cast<const float4*>(p + 12);
        float2 a4 = *reinterpret_cast<const float2*>(p + 16);
        // xr[i] = halo col (col0 + i); output col j, tap kw uses xr[j+kw]
        float xr[18] = {a0.x, a0.y, a0.z, a0.w, a1.x, a1.y, a1.z, a1.w,
                        a2.x, a2.y, a2.z, a2.w, a3.x, a3.y, a3.z, a3.w,
                        a4.x, a4.y};
#pragma unroll
        for (int kw = 0; kw < 3; ++kw) {
          float4 wq = *reinterpret_cast<const float4*>(&wsm[ci][kh * 3 + kw][cog4 * 4]);
          float wv[4] = {wq.x, wq.y, wq.z, wq.w};
#pragma unroll
          for (int co = 0; co < 4; ++co)
#pragma unroll
            for (int j = 0; j < 16; ++j)
              acc[co][j] = fmaf(xr[j + kw], wv[co], acc[co][j]);
        }
      }
    }
    __syncthreads();
  }

  const int h = h0 + r2;
#pragma unroll
  for (int co = 0; co < 4; ++co) {
    int c = cout0 + cog4 * 4 + co;
    float bv = bias[c];
#pragma unroll
    for (int j = 0; j < 16; ++j) {
      int ww = w0 + col0 + j;
      if (ww < W) {
        float v = acc[co][j] + bv;
        t[((size_t)(n * CCH + c) * H + h) * W + ww] = v > 0.f ? v : 0.f;
      }
    }
  }
}

// K1a: level-0 conv (H=W=256), grid (4,64,8)
__global__ __launch_bounds__(256, 3)
void k_conv0(const float* __restrict__ x, const float* __restrict__ wT,
             const float* __restrict__ bias, float* __restrict__ t) {
  int n = blockIdx.z >> 2, cog = blockIdx.z & 3;
  conv_body(x, wT, bias, t, 256, 256, n, cog, blockIdx.y * 4, blockIdx.x * 64);
}

// K1b: fused conv for levels 1-4 (736 blocks, 1D grid, block table)
__global__ __launch_bounds__(256, 3)
void k_conv4(const float* __restrict__ f1, const float* __restrict__ f2,
             const float* __restrict__ f3, const float* __restrict__ f4,
             const float* __restrict__ wT, const float* __restrict__ bias,
             float* __restrict__ t) {
  int b = blockIdx.x;
  const float* x; float* tb; int H, gx, gy, l;
  if (b < 512)      { x = f1; tb = t;            H = 128; gx = 2; gy = 32; l = b; }
  else if (b < 640) { x = f2; tb = t +  8388608; H =  64; gx = 1; gy = 16; l = b - 512; }
  else if (b < 704) { x = f3; tb = t + 10485760; H =  32; gx = 1; gy =  8; l = b - 640; }
  else              { x = f4; tb = t + 11010048; H =  16; gx = 1; gy =  4; l = b - 704; }
  int bx = l % gx;
  int by = (l / gx) % gy;
  int bz = l / (gx * gy);
  int n = bz >> 2, cog = bz & 3;
  conv_body(x, wT, bias, tb, H, H, n, cog, by * 4, bx * 64);
}

// ---------------- 1x1 heads body (4 pixels/thread, float4 loads) ----------
__device__ __forceinline__ void heads_body(
    const float* __restrict__ t,
    const float* __restrict__ wobj, const float* __restrict__ bobj,
    const float* __restrict__ wdel, const float* __restrict__ bdel,
    float* __restrict__ logits, float4* __restrict__ deltas,
    int HW, int loff, int n, int p0) {
  __shared__ float wl[15][256];
  __shared__ float bl[15];
  for (int i = threadIdx.x; i < 15 * 256; i += 256) {
    int o = i >> 8, c = i & 255;
    wl[o][c] = (o < 3) ? wobj[o * 256 + c] : wdel[(o - 3) * 256 + c];
  }
  if (threadIdx.x < 15)
    bl[threadIdx.x] = (threadIdx.x < 3) ? bobj[threadIdx.x] : bdel[threadIdx.x - 3];
  __syncthreads();
  if (p0 >= HW) return;

  float4 acc[15];
#pragma unroll
  for (int o = 0; o < 15; ++o) acc[o] = make_float4(0.f, 0.f, 0.f, 0.f);
  const float* tp = t + (size_t)n * CCH * HW + p0;
  for (int c = 0; c < 256; ++c) {
    float4 v = *reinterpret_cast<const float4*>(tp + (size_t)c * HW);
#pragma unroll
    for (int o = 0; o < 15; ++o) {
      float wv = wl[o][c];
      acc[o].x = fmaf(v.x, wv, acc[o].x);
      acc[o].y = fmaf(v.y, wv, acc[o].y);
      acc[o].z = fmaf(v.z, wv, acc[o].z);
      acc[o].w = fmaf(v.w, wv, acc[o].w);
    }
  }
#pragma unroll
  for (int o = 0; o < 15; ++o) {
    float bv = bl[o];
    acc[o].x += bv; acc[o].y += bv; acc[o].z += bv; acc[o].w += bv;
  }

  const float* af = reinterpret_cast<const float*>(acc);
  size_t base = (size_t)n * LTOT + loff + (size_t)p0 * 3;
#pragma unroll
  for (int i2 = 0; i2 < 4; ++i2) {
#pragma unroll
    for (int a = 0; a < 3; ++a) {
      logits[base + i2 * 3 + a] = af[a * 4 + i2];
      deltas[base + i2 * 3 + a] =
          make_float4(af[(3 + a * 4 + 0) * 4 + i2], af[(3 + a * 4 + 1) * 4 + i2],
                      af[(3 + a * 4 + 2) * 4 + i2], af[(3 + a * 4 + 3) * 4 + i2]);
    }
  }
}

__global__ __launch_bounds__(256)
void k_heads0(const float* __restrict__ t,
              const float* __restrict__ wobj, const float* __restrict__ bobj,
              const float* __restrict__ wdel, const float* __restrict__ bdel,
              float* __restrict__ logits, float4* __restrict__ deltas) {
  heads_body(t, wobj, bobj, wdel, bdel, logits, deltas,
             65536, 0, blockIdx.y, (blockIdx.x * 256 + threadIdx.x) * 4);
}

__global__ __launch_bounds__(256)
void k_heads4(const float* __restrict__ t,
              const float* __restrict__ wobj, const float* __restrict__ bobj,
              const float* __restrict__ wdel, const float* __restrict__ bdel,
              float* __restrict__ logits, float4* __restrict__ deltas) {
  int b = blockIdx.x;
  const float* tb; int HW, loff, start;
  if (b < 16)      { tb = t;            HW = 16384; loff = 196608; start = 0;  }
  else if (b < 20) { tb = t +  8388608; HW =  4096; loff = 245760; start = 16; }
  else if (b < 21) { tb = t + 10485760; HW =  1024; loff = 258048; start = 20; }
  else             { tb = t + 11010048; HW =   256; loff = 261120; start = 21; }
  heads_body(tb, wobj, bobj, wdel, bdel, logits, deltas,
             HW, loff, blockIdx.y, ((b - start) * 256 + threadIdx.x) * 4);
}

// ---------------- K3: per-(n,level) exact stable top-k + box decode -------
__global__ __launch_bounds__(1024)
void k_topk(const float* __restrict__ logits, const float4* __restrict__ deltas,
            float* __restrict__ scat, float4* __restrict__ bout,
            double* __restrict__ obout, unsigned* __restrict__ valid) {
  constexpr int   Hs[5]    = {256, 128, 64, 32, 16};
  constexpr int   strd[5]  = {4, 8, 16, 32, 64};
  constexpr float szs[5]   = {32.f, 64.f, 128.f, 256.f, 512.f};
  constexpr int   loffs[5] = {0, 196608, 245760, 258048, 261120};
  constexpr int   Ms[5]    = {196608, 49152, 12288, 3072, 768};
  constexpr int   ksz[5]   = {1000, 1000, 1000, 1000, 768};
  constexpr int   coffs[5] = {0, 1000, 2000, 3000, 4000};

  __shared__ unsigned hist[2048];
  __shared__ unsigned long long cand[1024];
  __shared__ unsigned tie[1024];
  __shared__ unsigned sB1, sC1, sB2, sC2, sDK, sTN;
  __shared__ unsigned cntG, cntT;

  const int task = blockIdx.x;
  const int n = task / 5, lvl = task % 5;
  const int M = Ms[lvl], K = ksz[lvl], loff = loffs[lvl];
  const float* lg = logits + (size_t)n * LTOT + loff;
  const int tid = threadIdx.x;

  for (int i = tid; i < 2048; i += 1024) hist[i] = 0;
  if (tid == 0) { cntG = 0; cntT = 0; }
  __syncthreads();
  for (int i = tid; i < M; i += 1024) atomicAdd(&hist[keyd(lg[i]) >> 21], 1u);
  __syncthreads();
  if (tid == 0) {
    unsigned acc = 0;
    for (int b = 2047; b >= 0; --b) {
      unsigned na = acc + hist[b];
      if (na >= (unsigned)K) { sB1 = (unsigned)b; sC1 = acc; break; }
      acc = na;
    }
  }
  __syncthreads();
  const unsigned B1 = sB1;
  const unsigned rem1 = (unsigned)K - sC1;

  for (int i = tid; i < 2048; i += 1024) hist[i] = 0;
  __syncthreads();
  for (int i = tid; i < M; i += 1024) {
    unsigned d = keyd(lg[i]);
    if ((d >> 21) == B1) atomicAdd(&hist[(d >> 10) & 0x7FFu], 1u);
  }
  __syncthreads();
  if (tid == 0) {
    unsigned acc = 0;
    for (int b = 2047; b >= 0; --b) {
      unsigned na = acc + hist[b];
      if (na >= rem1) { sB2 = (unsigned)b; sC2 = acc; break; }
      acc = na;
    }
  }
  __syncthreads();
  const unsigned B2 = sB2;
  const unsigned rem2 = rem1 - sC2;
  const unsigned pfx = (B1 << 11) | B2;

  for (int i = tid; i < 1024; i += 1024) hist[i] = 0;
  __syncthreads();
  for (int i = tid; i < M; i += 1024) {
    unsigned d = keyd(lg[i]);
    if ((d >> 10) == pfx) atomicAdd(&hist[d & 0x3FFu], 1u);
  }
  __syncthreads();
  if (tid == 0) {
    unsigned acc = 0;
    for (int b = 1023; b >= 0; --b) {
      unsigned na = acc + hist[b];
      if (na >= rem2) { sDK = (pfx << 10) | (unsigned)b; sTN = rem2 - acc; break; }
      acc = na;
    }
  }
  __syncthreads();
  const unsigned dk = sDK;
  const unsigned tneed = sTN;
  const unsigned cg = (unsigned)K - tneed;

  for (int i = tid; i < M; i += 1024) {
    unsigned d = keyd(lg[i]);
    if (d > dk) {
      unsigned p = atomicAdd(&cntG, 1u);
      cand[p] = ((unsigned long long)(~d) << 32) | (unsigned)i;
    } else if (d == dk) {
      unsigned q = atomicAdd(&cntT, 1u);
      if (q < 1024u) tie[q] = (unsigned)i;
    }
  }
  __syncthreads();
  if (tid == 0) {
    int ct = (int)(cntT < 1024u ? cntT : 1024u);
    for (int a = 1; a < ct; ++a) {
      unsigned v = tie[a]; int b = a - 1;
      while (b >= 0 && tie[b] > v) { tie[b + 1] = tie[b]; --b; }
      tie[b + 1] = v;
    }
    for (unsigned q = 0; q < tneed; ++q)
      cand[cg + q] = ((unsigned long long)(~dk) << 32) | tie[q];
  }
  __syncthreads();
  if (tid >= K) cand[tid] = ~0ULL;
  __syncthreads();

  for (unsigned k2 = 2; k2 <= 1024; k2 <<= 1)
    for (unsigned j = k2 >> 1; j > 0; j >>= 1) {
      __syncthreads();
      unsigned i = (unsigned)tid, l = i ^ j;
      if (l > i) {
        unsigned long long a = cand[i], b = cand[l];
        bool up = ((i & k2) == 0);
        if (up ? (a > b) : (a < b)) { cand[i] = b; cand[l] = a; }
      }
    }
  __syncthreads();

  if (tid < K) {
    unsigned long long kk = cand[tid];
    unsigned idx = (unsigned)kk;
    unsigned d = ~(unsigned)(kk >> 32);
    float s = invkey(d);
    int catpos = n * MCAT + coffs[lvl] + tid;
    scat[catpos] = s;

    int a = idx % 3;
    int pix = idx / 3;
    int W = Hs[lvl];
    int hh = pix / W;
    int ww = pix - hh * W;
    float4 d4 = deltas[(size_t)n * LTOT + loff + idx];

    double r  = (a == 0) ? 0.5 : (a == 1 ? 1.0 : 2.0);
    double sz = (double)szs[lvl];
    double cw = sz / sqrt(r);
    double ch = cw * r;
    double cx = (double)(ww * strd[lvl]);
    double cy = (double)(hh * strd[lvl]);
    double dx = (double)d4.x, dy = (double)d4.y;
    double dw = (double)d4.z; if (dw > SCALE_CLAMP_D) dw = SCALE_CLAMP_D;
    double dh = (double)d4.w; if (dh > SCALE_CLAMP_D) dh = SCALE_CLAMP_D;
    double pcx = dx * cw + cx, pcy = dy * ch + cy;
    double pw = exp(dw) * cw,  ph = exp(dh) * ch;
    double x0 = pcx - 0.5 * pw, y0 = pcy - 0.5 * ph;
    double x1 = pcx + 0.5 * pw, y1 = pcy + 0.5 * ph;
    x0 = x0 < 0.0 ? 0.0 : (x0 > 1024.0 ? 1024.0 : x0);
    y0 = y0 < 0.0 ? 0.0 : (y0 > 1024.0 ? 1024.0 : y0);
    x1 = x1 < 0.0 ? 0.0 : (x1 > 1024.0 ? 1024.0 : x1);
    y1 = y1 < 0.0 ? 0.0 : (y1 > 1024.0 ? 1024.0 : y1);
    bool vld = ((x1 - x0) > 0.0) && ((y1 - y0) > 0.0);

    bout[catpos] = make_float4((float)x0, (float)y0, (float)x1, (float)y1);
    double off = (double)lvl * 4096.0;
    double* op = obout + (size_t)catpos * 4;
    op[0] = x0 + off; op[1] = y0 + off; op[2] = x1 + off; op[3] = y1 + off;
    valid[catpos] = vld ? 1u : 0u;
  }
}

// ---------------- K4: per-image stable sort of 4768 candidates ------------
__global__ __launch_bounds__(1024)
void k_sort(const float* __restrict__ scat, const float4* __restrict__ b,
            const double* __restrict__ ob, const unsigned* __restrict__ valid,
            float* __restrict__ s_s, float4* __restrict__ b_s,
            double* __restrict__ ob_s, unsigned* __restrict__ valid_s) {
  __shared__ unsigned long long sk[8192];
  const int n = blockIdx.x;
  const int tid = threadIdx.x;
  for (int i = tid; i < 8192; i += 1024)
    sk[i] = (i < MCAT)
      ? ((unsigned long long)(~keyd(scat[n * MCAT + i])) << 32) | (unsigned)i
      : ~0ULL;
  __syncthreads();
  for (unsigned k2 = 2; k2 <= 8192; k2 <<= 1)
    for (unsigned j = k2 >> 1; j > 0; j >>= 1) {
      for (int m = 0; m < 8; ++m) {
        unsigned i = (unsigned)tid + (unsigned)m * 1024u;
        unsigned l = i ^ j;
        if (l > i) {
          unsigned long long a = sk[i], bb = sk[l];
          bool up = ((i & k2) == 0);
          if (up ? (a > bb) : (a < bb)) { sk[i] = bb; sk[l] = a; }
        }
      }
      __syncthreads();
    }
  for (int r = tid; r < MCAT; r += 1024) {
    unsigned long long kk = sk[r];
    unsigned pos = (unsigned)kk;
    unsigned d = ~(unsigned)(kk >> 32);
    s_s[n * MCAT + r] = invkey(d);
    b_s[n * MCAT + r] = b[n * MCAT + pos];
    const double* src = ob + ((size_t)n * MCAT + pos) * 4;
    double* dst = ob_s + ((size_t)n * MCAT + r) * 4;
    dst[0] = src[0]; dst[1] = src[1]; dst[2] = src[2]; dst[3] = src[3];
    valid_s[n * MCAT + r] = valid[n * MCAT + pos];
  }
}

// ---------------- K5: suppression bitmask (fp64 IoU, j>i bits) ------------
__global__ __launch_bounds__(256)
void k_mask(const double* __restrict__ ob_s, unsigned long long* __restrict__ mask) {
  const int n = blockIdx.y;
  const int i = blockIdx.x;
  const double* bi = ob_s + ((size_t)n * MCAT + i) * 4;
  const double ix0 = bi[0], iy0 = bi[1], ix1 = bi[2], iy1 = bi[3];
  const double ai = (ix1 - ix0) * (iy1 - iy0);
  const int tid = threadIdx.x;
  for (int j0 = 0; j0 < MCAT; j0 += 256) {
    int j = j0 + tid;
    bool sup = false;
    if (j < MCAT && j > i) {
      const double* bj = ob_s + ((size_t)n * MCAT + j) * 4;
      double jx0 = bj[0], jy0 = bj[1], jx1 = bj[2], jy1 = bj[3];
      double aj = (jx1 - jx0) * (jy1 - jy0);
      double lx = ix0 > jx0 ? ix0 : jx0;
      double ly = iy0 > jy0 ? iy0 : jy0;
      double rx = ix1 < jx1 ? ix1 : jx1;
      double ry = iy1 < jy1 ? iy1 : jy1;
      double wx = rx - lx; wx = wx > 0.0 ? wx : 0.0;
      double wy = ry - ly; wy = wy > 0.0 ? wy : 0.0;
      double inter = wx * wy;
      double iou = inter / (ai + aj - inter + 1e-9);
      sup = iou > 0.7;
    }
    unsigned long long bal = __ballot(sup);
    if ((tid & 63) == 0) {
      int word = (j0 + tid) >> 6;
      if (word < MW) mask[((size_t)n * MCAT + i) * MW + word] = bal;
    }
  }
}

// ---------------- K6: greedy NMS scan (parallel rem-update) + output ------
__global__ __launch_bounds__(256)
void k_nms(const unsigned long long* __restrict__ mask,
           const unsigned* __restrict__ valid_s,
           const float* __restrict__ s_s, const float4* __restrict__ b_s,
           float* __restrict__ out) {
  __shared__ unsigned long long rem[MW];
  __shared__ unsigned long long supcc[64];
  __shared__ unsigned long long keepw[MW];
  __shared__ int kl[64];
  __shared__ int snk;
  __shared__ unsigned kpfx[MW], nkpfx[MW];
  __shared__ unsigned sKept;
  const int n = blockIdx.x;
  const int tid = threadIdx.x;
  const unsigned long long* msk = mask + (size_t)n * MCAT * MW;

  for (int w = tid; w < MW; w += 256) {
    unsigned long long r = 0ULL;
    for (int b = 0; b < 64; ++b) {
      int i = w * 64 + b;
      bool rm = (i >= MCAT) || (valid_s[n * MCAT + i] == 0u);
      if (rm) r |= (1ULL << b);
    }
    rem[w] = r;
    keepw[w] = 0ULL;
  }
  __syncthreads();

  for (int c = 0; c < MW; ++c) {
    if (tid < 64) {
      int i = c * 64 + tid;
      supcc[tid] = (i < MCAT) ? msk[(size_t)i * MW + c] : 0ULL;
    }
    __syncthreads();
    if (tid == 0) {
      unsigned long long r = rem[c], km = 0ULL;
      int nk = 0;
      for (int b = 0; b < 64; ++b) {
        if (!((r >> b) & 1ULL)) { km |= (1ULL << b); kl[nk++] = b; r |= supcc[b]; }
      }
      rem[c] = r; keepw[c] = km; snk = nk;
    }
    __syncthreads();
    const int nk = snk;
    const int nw = MW - 1 - c;
    const int total = nk * nw;
    for (int idx = tid; idx < total; idx += 256) {
      int b = kl[idx / nw];
      int w = c + 1 + (idx % nw);
      unsigned long long v = msk[(size_t)(c * 64 + b) * MW + w];
      if (v) atomicOr(&rem[w], v);
    }
    __syncthreads();
  }

  if (tid == 0) {
    unsigned ka = 0, na = 0;
    for (int w = 0; w < MW; ++w) {
      kpfx[w] = ka; nkpfx[w] = na;
      unsigned long long range = (w < MW - 1) ? ~0ULL : ((1ULL << 32) - 1ULL);
      ka += (unsigned)__popcll(keepw[w]);
      na += (unsigned)__popcll((~keepw[w]) & range);
    }
    sKept = ka;
  }
  __syncthreads();
  const unsigned keptTotal = sKept;

  for (int i = tid; i < MCAT; i += 256) {
    int w = i >> 6, b = i & 63;
    unsigned long long below = (1ULL << b) - 1ULL;
    bool kept = (keepw[w] >> b) & 1ULL;
    unsigned row;
    if (kept)
      row = kpfx[w] + (unsigned)__popcll(keepw[w] & below);
    else
      row = keptTotal + nkpfx[w] + (unsigned)__popcll((~keepw[w]) & below);
    if (row < 1000u) {
      float4 bb = b_s[n * MCAT + i];
      float sc = kept ? s_s[n * MCAT + i] : -1e4f;
      float* o = out + ((size_t)n * 1000 + row) * 5;
      o[0] = bb.x; o[1] = bb.y; o[2] = bb.z; o[3] = bb.w; o[4] = sc;
    }
  }
}

// ---------------- launch ----------------
extern "C" void kernel_launch(void* const* d_in, const int* in_sizes, int n_in,
                              void* d_out, int out_size, void* d_ws, size_t ws_size,
                              hipStream_t stream) {
  (void)in_sizes; (void)n_in; (void)out_size;
  const float* feats[5] = {(const float*)d_in[0], (const float*)d_in[1],
                           (const float*)d_in[2], (const float*)d_in[3],
                           (const float*)d_in[4]};
  const float* w_conv = (const float*)d_in[5];
  const float* b_conv = (const float*)d_in[6];
  const float* w_obj  = (const float*)d_in[7];
  const float* b_obj  = (const float*)d_in[8];
  const float* w_del  = (const float*)d_in[9];
  const float* b_del  = (const float*)d_in[10];
  float* out = (float*)d_out;

  char* p = (char*)d_ws;
  auto alloc = [&](size_t bytes) -> void* {
    void* r = (void*)p;
    p += (bytes + 255) & ~(size_t)255;
    return r;
  };
  float*  t       = (float*)  alloc((size_t)2 * 256 * 256 * 256 * 4); // 134 MB, lvl1-4 then lvl0
  float*  wT      = (float*)  alloc((size_t)2304 * 256 * 4);
  float*  logits  = (float*)  alloc((size_t)NIMG * LTOT * 4);
  float4* deltas  = (float4*) alloc((size_t)NIMG * LTOT * 16);
  float*  scat    = (float*)  alloc((size_t)NIMG * MCAT * 4);
  float4* bout    = (float4*) alloc((size_t)NIMG * MCAT * 16);
  double* obout   = (double*) alloc((size_t)NIMG * MCAT * 32);
  unsigned* valid = (unsigned*)alloc((size_t)NIMG * MCAT * 4);
  float*  s_s     = (float*)  alloc((size_t)NIMG * MCAT * 4);
  float4* b_s     = (float4*) alloc((size_t)NIMG * MCAT * 16);
  double* ob_s    = (double*) alloc((size_t)NIMG * MCAT * 32);
  unsigned* val_s = (unsigned*)alloc((size_t)NIMG * MCAT * 4);
  unsigned long long* mask =
      (unsigned long long*)alloc((size_t)NIMG * MCAT * MW * 8);
  if ((size_t)(p - (char*)d_ws) > ws_size) return;

  k_wT<<<2304, 256, 0, stream>>>(w_conv, wT);

  // levels 1-4 fused (t[0..11141120)), heads4 consumes, then level 0 reuses t
  k_conv4<<<736, 256, 0, stream>>>(feats[1], feats[2], feats[3], feats[4],
                                   wT, b_conv, t);
  k_heads4<<<dim3(22, 2), 256, 0, stream>>>(t, w_obj, b_obj, w_del, b_del,
                                            logits, deltas);
  k_conv0<<<dim3(4, 64, 8), 256, 0, stream>>>(feats[0], wT, b_conv, t);
  k_heads0<<<dim3(64, 2), 256, 0, stream>>>(t, w_obj, b_obj, w_del, b_del,
                                            logits, deltas);

  k_topk<<<10, 1024, 0, stream>>>(logits, deltas, scat, bout, obout, valid);
  k_sort<<<2, 1024, 0, stream>>>(scat, bout, obout, valid, s_s, b_s, ob_s, val_s);
  k_mask<<<dim3(MCAT, 2), 256, 0, stream>>>(ob_s, mask);
  k_nms<<<2, 256, 0, stream>>>(mask, val_s, s_s, b_s, out);
}